// Round 2
// baseline (1789.342 us; speedup 1.0000x reference)
//
#include <hip/hip_runtime.h>
#include <cstddef>
#include <cstdint>

// ---------------- problem constants ----------------
static constexpr int BN_   = 2;     // batch
static constexpr int L_    = 1024;  // sequence length (W/4)
static constexpr int DM_   = 512;   // d_model
static constexpr int EPROJ = 2192;  // in_proj out dim
static constexpr int DI_   = 1024;  // d_inner
static constexpr int CONVD = 1152;  // conv dim
static constexpr int HN_   = 16;    // heads
static constexpr int FH_   = 1024;  // ff hidden

// workspace float offsets
static constexpr size_t O_CONV1 = 0;                       // 2,097,152  (reused as y)
static constexpr size_t O_CONV2 = 2097152;                 // 1,048,576  (reused as proj)
static constexpr size_t O_TOKA  = O_CONV2 + 1048576;       // 1,048,576
static constexpr size_t O_TOKB  = O_TOKA + 1048576;        // 1,048,576
static constexpr size_t O_ZX    = O_TOKB + 1048576;        // 4,489,216
static constexpr size_t O_XBC   = O_ZX + 4489216;          // 2,359,296  (reused as ffh)
static constexpr size_t O_DT    = O_XBC + 2359296;         // 32,768
static constexpr size_t O_DA    = O_DT + 32768;            // 32,768
static constexpr size_t O_FFO   = O_DA + 32768;            // 1,048,576
static constexpr size_t O_STATS = O_FFO + 1048576;         // 16,672
static constexpr size_t STATS_SZ = 16672;

__device__ __forceinline__ float sigm(float x) { return 1.f / (1.f + expf(-x)); }

// ---------------- conv stem ----------------
__global__ __launch_bounds__(256) void conv1_k(const float* __restrict__ img,
                                               const float* __restrict__ w,
                                               float* __restrict__ out) {
  int idx = blockIdx.x * 256 + threadIdx.x;               // 524288 threads, 4 outputs each
  int xq = idx & 511, y = (idx >> 9) & 31, c = (idx >> 14) & 15, b = idx >> 18;
  __shared__ float ws[49];
  if (threadIdx.x < 49) ws[threadIdx.x] = w[c * 49 + threadIdx.x];
  __syncthreads();
  int x0 = xq * 4;
  int ix0 = 2 * x0 - 3;
  float acc[4] = {0.f, 0.f, 0.f, 0.f};
  for (int ky = 0; ky < 7; ++ky) {
    int iy = 2 * y - 3 + ky;
    if ((unsigned)iy >= 64u) continue;
    const float* irow = img + ((size_t)b * 64 + iy) * 4096;
    float in[13];
#pragma unroll
    for (int t = 0; t < 13; ++t) {
      int ix = ix0 + t;
      in[t] = ((unsigned)ix < 4096u) ? irow[ix] : 0.f;
    }
#pragma unroll
    for (int kx = 0; kx < 7; ++kx) {
      float wv = ws[ky * 7 + kx];
#pragma unroll
      for (int j = 0; j < 4; ++j) acc[j] += in[2 * j + kx] * wv;
    }
  }
  float4 o; o.x = acc[0]; o.y = acc[1]; o.z = acc[2]; o.w = acc[3];
  *reinterpret_cast<float4*>(&out[(size_t)idx * 4]) = o;
}

__global__ __launch_bounds__(256) void conv2_k(const float* __restrict__ inp,
                                               const float* __restrict__ w,
                                               float* __restrict__ out) {
  int idx = blockIdx.x * 256 + threadIdx.x;               // 262144 threads, 4 outputs each
  int xq = idx & 255, y = (idx >> 8) & 15, c2 = (idx >> 12) & 31, b = idx >> 17;
  __shared__ float ws[784];
  for (int t = threadIdx.x; t < 784; t += 256) ws[t] = w[c2 * 784 + t];
  __syncthreads();
  int x0 = xq * 4;
  int ix0 = 2 * x0 - 3;
  float acc[4] = {0.f, 0.f, 0.f, 0.f};
  for (int c1 = 0; c1 < 16; ++c1) {
    const float* ch = inp + ((size_t)(b * 16 + c1) * 32) * 2048;
    for (int ky = 0; ky < 7; ++ky) {
      int iy = 2 * y - 3 + ky;
      if ((unsigned)iy >= 32u) continue;
      const float* irow = ch + (size_t)iy * 2048;
      float in[13];
#pragma unroll
      for (int t = 0; t < 13; ++t) {
        int ix = ix0 + t;
        in[t] = ((unsigned)ix < 2048u) ? irow[ix] : 0.f;
      }
#pragma unroll
      for (int kx = 0; kx < 7; ++kx) {
        float wv = ws[c1 * 49 + ky * 7 + kx];
#pragma unroll
        for (int j = 0; j < 4; ++j) acc[j] += in[2 * j + kx] * wv;
      }
    }
  }
  float4 o; o.x = acc[0]; o.y = acc[1]; o.z = acc[2]; o.w = acc[3];
  *reinterpret_cast<float4*>(&out[(size_t)idx * 4]) = o;
}

// per-channel stats for [B][C][S] tensor -> atomicAdd into sums[c], sums[C+c]
__global__ __launch_bounds__(256) void stats_chan_k(const float* __restrict__ X,
                                                    float* __restrict__ sums,
                                                    int C, int S, int Bc) {
  int c = blockIdx.x, tid = threadIdx.x;
  float s = 0.f, q = 0.f;
  for (int b = 0; b < Bc; ++b) {
    const float* base = X + ((size_t)b * C + c) * S;
    for (int i = blockIdx.y * 256 + tid; i < S; i += gridDim.y * 256) {
      float v = base[i]; s += v; q += v * v;
    }
  }
  for (int o = 32; o > 0; o >>= 1) { s += __shfl_down(s, o); q += __shfl_down(q, o); }
  __shared__ float rs[4], rq[4];
  if ((tid & 63) == 0) { rs[tid >> 6] = s; rq[tid >> 6] = q; }
  __syncthreads();
  if (tid == 0) {
    atomicAdd(&sums[c], rs[0] + rs[1] + rs[2] + rs[3]);
    atomicAdd(&sums[C + c], rq[0] + rq[1] + rq[2] + rq[3]);
  }
}

__global__ void finalize_bn_k(const float* __restrict__ sums, const float* __restrict__ g,
                              const float* __restrict__ b, float* __restrict__ sc,
                              float* __restrict__ sh, int C, float inv) {
  int c = blockIdx.x * blockDim.x + threadIdx.x;
  if (c >= C) return;
  float mean = sums[c] * inv;
  float var = sums[C + c] * inv - mean * mean;
  float s = g[c] * rsqrtf(var + 1e-5f);
  sc[c] = s; sh[c] = b[c] - mean * s;
}

__global__ __launch_bounds__(256) void apply_bn1_k(float* __restrict__ x,
                                                   const float* __restrict__ sc,
                                                   const float* __restrict__ sh) {
  int idx = blockIdx.x * 256 + threadIdx.x;
  int c = (idx >> 16) & 15;                               // 32*2048 = 65536 per channel
  x[idx] = sc[c] * x[idx] + sh[c];
}

__global__ __launch_bounds__(256) void img_stats_k(const float* __restrict__ img,
                                                   float* __restrict__ sums) {
  int idx = blockIdx.x * 256 + threadIdx.x;               // 32768 samples
  int xx = idx & 1023, yy = (idx >> 10) & 15, b = idx >> 14;
  float v = img[((size_t)b * 64 + yy * 4) * 4096 + xx * 4];
  float s = v, q = v * v;
  for (int o = 32; o > 0; o >>= 1) { s += __shfl_down(s, o); q += __shfl_down(q, o); }
  __shared__ float rs[4], rq[4];
  if ((threadIdx.x & 63) == 0) { rs[threadIdx.x >> 6] = s; rq[threadIdx.x >> 6] = q; }
  __syncthreads();
  if (threadIdx.x == 0) {
    atomicAdd(&sums[0], rs[0] + rs[1] + rs[2] + rs[3]);
    atomicAdd(&sums[1], rq[0] + rq[1] + rq[2] + rq[3]);
  }
}

__global__ void ds_fin_k(const float* __restrict__ sums, const float* __restrict__ dsw,
                         const float* __restrict__ g, const float* __restrict__ b,
                         float* __restrict__ sc, float* __restrict__ sh) {
  int c = threadIdx.x;
  if (c >= 32) return;
  float m = sums[0] * (1.f / 32768.f);
  float var = sums[1] * (1.f / 32768.f) - m * m;
  float wv = dsw[c];
  float s = g[c] * rsqrtf(wv * wv * var + 1e-5f);
  // bn(w*sample) = (w*s)*sample + (b - w*m*s)   <-- scale must carry the conv weight
  sc[c] = wv * s; sh[c] = b[c] - wv * m * s;
}

// h = relu(bn2(conv2) + bn_ds(ds)); write tokens in (B, L, C) layout
__global__ __launch_bounds__(256) void stem_fuse_k(const float* __restrict__ conv2,
                                                   const float* __restrict__ img,
                                                   const float* __restrict__ s2, const float* __restrict__ t2,
                                                   const float* __restrict__ sds, const float* __restrict__ tds,
                                                   float* __restrict__ tok) {
  int idx = blockIdx.x * 256 + threadIdx.x;               // 2*1024*512
  int d = idx & 511, l = (idx >> 9) & 1023, b = idx >> 19;
  int c = d >> 4, hh = d & 15;
  float v = s2[c] * conv2[((size_t)(b * 32 + c) * 16 + hh) * 1024 + l] + t2[c]
          + sds[c] * img[((size_t)b * 64 + hh * 4) * 4096 + l * 4] + tds[c];
  tok[idx] = fmaxf(v, 0.f);
}

// ---------------- GEMM: Out(MxN) = A(MxK) @ W(NxK)^T (+bias) ----------------
template <int BM, int BN, int TM, int TN>
__global__ __launch_bounds__(256) void gemm_k(const float* __restrict__ A,
                                              const float* __restrict__ W,
                                              const float* __restrict__ bias,
                                              float* __restrict__ Out,
                                              int M, int N, int K) {
  constexpr int BK = 16;
  __shared__ float As[BK][BM + 4];
  __shared__ float Ws[BK][BN + 4];
  const int tid = threadIdx.x;
  const int bm = blockIdx.y * BM;
  const int bn = blockIdx.x * BN;
  const int tm = (tid >> 4) * TM;
  const int tn = (tid & 15) * TN;
  float acc[TM][TN];
#pragma unroll
  for (int i = 0; i < TM; ++i)
#pragma unroll
    for (int j = 0; j < TN; ++j) acc[i][j] = 0.f;
  const int r0 = tid >> 2;
  const int kk = (tid & 3) * 4;
  for (int k0 = 0; k0 < K; k0 += BK) {
#pragma unroll
    for (int rr = 0; rr < BM / 64; ++rr) {
      int r = r0 + rr * 64;
      float4 v = *reinterpret_cast<const float4*>(&A[(size_t)(bm + r) * K + k0 + kk]);
      As[kk + 0][r] = v.x; As[kk + 1][r] = v.y; As[kk + 2][r] = v.z; As[kk + 3][r] = v.w;
    }
#pragma unroll
    for (int rr = 0; rr < BN / 64; ++rr) {
      int r = r0 + rr * 64;
      int e = bn + r;
      float4 v = make_float4(0.f, 0.f, 0.f, 0.f);
      if (e < N) v = *reinterpret_cast<const float4*>(&W[(size_t)e * K + k0 + kk]);
      Ws[kk + 0][r] = v.x; Ws[kk + 1][r] = v.y; Ws[kk + 2][r] = v.z; Ws[kk + 3][r] = v.w;
    }
    __syncthreads();
#pragma unroll
    for (int k = 0; k < BK; ++k) {
      float af[TM], bf[TN];
#pragma unroll
      for (int i = 0; i < TM / 4; ++i)
        *reinterpret_cast<float4*>(&af[i * 4]) = *reinterpret_cast<float4*>(&As[k][tm + i * 4]);
#pragma unroll
      for (int j = 0; j < TN / 4; ++j)
        *reinterpret_cast<float4*>(&bf[j * 4]) = *reinterpret_cast<float4*>(&Ws[k][tn + j * 4]);
#pragma unroll
      for (int i = 0; i < TM; ++i)
#pragma unroll
        for (int j = 0; j < TN; ++j) acc[i][j] += af[i] * bf[j];
    }
    __syncthreads();
  }
#pragma unroll
  for (int i = 0; i < TM; ++i) {
    int row = bm + tm + i;
#pragma unroll
    for (int j4 = 0; j4 < TN / 4; ++j4) {
      int col = bn + tn + j4 * 4;
      if (col < N) {
        float4 o;
        o.x = acc[i][j4 * 4 + 0]; o.y = acc[i][j4 * 4 + 1];
        o.z = acc[i][j4 * 4 + 2]; o.w = acc[i][j4 * 4 + 3];
        if (bias) {
          float4 bv = *reinterpret_cast<const float4*>(&bias[col]);
          o.x += bv.x; o.y += bv.y; o.z += bv.z; o.w += bv.w;
        }
        *reinterpret_cast<float4*>(&Out[(size_t)row * N + col]) = o;
      }
    }
  }
}

// ---------------- mamba pieces ----------------
__global__ __launch_bounds__(256) void dt_prep_k(const float* __restrict__ zx,
                                                 const float* __restrict__ dtb,
                                                 const float* __restrict__ alog,
                                                 float* __restrict__ dtO, float* __restrict__ dAO) {
  int idx = blockIdx.x * 256 + threadIdx.x;               // 32768
  int h = idx & 15, row = idx >> 4;
  float raw = zx[(size_t)row * EPROJ + 2176 + h] + dtb[h];
  float dt = raw > 20.f ? raw : log1pf(expf(raw));
  dtO[idx] = dt;
  dAO[idx] = expf(dt * (-expf(alog[h])));
}

__global__ __launch_bounds__(256) void conv_silu_k(const float* __restrict__ zx,
                                                   const float* __restrict__ cw,
                                                   const float* __restrict__ cb,
                                                   float* __restrict__ out) {
  int idx = blockIdx.x * 256 + threadIdx.x;               // 2*1024*1152
  int c = idx % CONVD;
  int row = idx / CONVD;
  int l = row & 1023, bb = row >> 10;
  float acc = cb[c];
#pragma unroll
  for (int k = 0; k < 4; ++k) {
    int ll = l - 3 + k;
    if (ll >= 0) acc += zx[((size_t)(bb * 1024 + ll)) * EPROJ + 1024 + c] * cw[c * 4 + k];
  }
  out[idx] = acc * sigm(acc);
}

// selective scan: 128 blocks = (b, head, p-group of 16); thread = (p_local, n-quarter)
__global__ __launch_bounds__(256) void scan_k(const float* __restrict__ xbc,
                                              const float* __restrict__ dtA,
                                              const float* __restrict__ dAA,
                                              const float* __restrict__ Dq,
                                              float* __restrict__ y) {
  constexpr int SCH = 16;
  int bid = blockIdx.x;
  int b = bid >> 6, rem = bid & 63, hh = rem >> 2, pg = rem & 3;
  int tid = threadIdx.x;
  int pl = tid >> 4, nq = tid & 15, n0 = nq * 4;
  int p = pg * 16 + pl;
  __shared__ float sB[2][SCH][64], sC[2][SCH][64], sx[2][SCH][16];
  __shared__ float sdt[2][SCH], sdA[2][SCH];
  const float* xb = xbc + (size_t)b * L_ * CONVD;
  const float* dtp = dtA + b * (L_ * HN_) + hh;
  const float* dAp = dAA + b * (L_ * HN_) + hh;
  float* yp_ = y + (size_t)b * L_ * DI_ + hh * 64 + p;
  float Dh = Dq[hh];
  float4 st = make_float4(0.f, 0.f, 0.f, 0.f);

  auto stage = [&](int l0, int buf) {
    int ll = tid >> 4, nn = (tid & 15) * 4;
    const float* base = xb + (size_t)(l0 + ll) * CONVD;
    *reinterpret_cast<float4*>(&sB[buf][ll][nn]) = *reinterpret_cast<const float4*>(base + 1024 + nn);
    *reinterpret_cast<float4*>(&sC[buf][ll][nn]) = *reinterpret_cast<const float4*>(base + 1088 + nn);
    if (nq < 4) {
      *reinterpret_cast<float4*>(&sx[buf][ll][nq * 4]) =
          *reinterpret_cast<const float4*>(base + hh * 64 + pg * 16 + nq * 4);
    } else if (nq == 4) {
      sdt[buf][ll] = dtp[(l0 + ll) * HN_];
    } else if (nq == 5) {
      sdA[buf][ll] = dAp[(l0 + ll) * HN_];
    }
  };

  stage(0, 0);
  int buf = 0;
  for (int c0 = 0; c0 < L_ / SCH; ++c0) {
    __syncthreads();
    if (c0 + 1 < L_ / SCH) stage((c0 + 1) * SCH, buf ^ 1);
    int l0 = c0 * SCH;
#pragma unroll
    for (int j = 0; j < SCH; ++j) {
      float xv = sx[buf][j][pl];
      float4 Bv = *reinterpret_cast<float4*>(&sB[buf][j][n0]);
      float4 Cv = *reinterpret_cast<float4*>(&sC[buf][j][n0]);
      float dtv = sdt[buf][j], dAv = sdA[buf][j];
      float co = dtv * xv;
      st.x = dAv * st.x + co * Bv.x;
      st.y = dAv * st.y + co * Bv.y;
      st.z = dAv * st.z + co * Bv.z;
      st.w = dAv * st.w + co * Bv.w;
      float yv = st.x * Cv.x + st.y * Cv.y + st.z * Cv.z + st.w * Cv.w;
      yv += __shfl_xor(yv, 1);
      yv += __shfl_xor(yv, 2);
      yv += __shfl_xor(yv, 4);
      yv += __shfl_xor(yv, 8);
      if (nq == 0) yp_[(size_t)(l0 + j) * DI_] = yv + Dh * xv;
    }
    buf ^= 1;
  }
}

// gated RMSNorm, in-place on y; z is cols [0,1024) of zxbcdt
__global__ __launch_bounds__(256) void rmsnorm_gate_k(float* __restrict__ y,
                                                      const float* __restrict__ zx,
                                                      const float* __restrict__ nw) {
  int row = blockIdx.x;
  float* yr = y + (size_t)row * DI_;
  const float* zr = zx + (size_t)row * EPROJ;
  int d0 = threadIdx.x * 4;
  float4 yv = *reinterpret_cast<float4*>(&yr[d0]);
  float4 zv = *reinterpret_cast<const float4*>(&zr[d0]);
  float4 g;
  g.x = yv.x * (zv.x * sigm(zv.x));
  g.y = yv.y * (zv.y * sigm(zv.y));
  g.z = yv.z * (zv.z * sigm(zv.z));
  g.w = yv.w * (zv.w * sigm(zv.w));
  float ss = g.x * g.x + g.y * g.y + g.z * g.z + g.w * g.w;
  for (int o = 32; o > 0; o >>= 1) ss += __shfl_down(ss, o);
  __shared__ float r4[4];
  __shared__ float tot;
  if ((threadIdx.x & 63) == 0) r4[threadIdx.x >> 6] = ss;
  __syncthreads();
  if (threadIdx.x == 0) tot = r4[0] + r4[1] + r4[2] + r4[3];
  __syncthreads();
  float rr = rsqrtf(tot * (1.f / DI_) + 1e-5f);
  float4 nwv = *reinterpret_cast<const float4*>(&nw[d0]);
  float4 o;
  o.x = g.x * rr * nwv.x; o.y = g.y * rr * nwv.y;
  o.z = g.z * rr * nwv.z; o.w = g.w * rr * nwv.w;
  *reinterpret_cast<float4*>(&yr[d0]) = o;
}

// column (per-channel) stats for row-major (rows x C)
__global__ __launch_bounds__(256) void colstats_k(const float* __restrict__ X,
                                                  float* __restrict__ sums, int C, int rows) {
  int c = blockIdx.x * 256 + threadIdx.x;
  int per = rows / gridDim.y;
  int r0 = blockIdx.y * per, r1 = r0 + per;
  float s = 0.f, q = 0.f;
  for (int r = r0; r < r1; ++r) { float v = X[(size_t)r * C + c]; s += v; q += v * v; }
  atomicAdd(&sums[c], s);
  atomicAdd(&sums[C + c], q);
}

__global__ __launch_bounds__(256) void apply_bn_k(const float* __restrict__ X,
                                                  const float* __restrict__ sc,
                                                  const float* __restrict__ sh,
                                                  const float* __restrict__ res,
                                                  float* __restrict__ out,
                                                  int n, int cmask, int relu) {
  int idx = blockIdx.x * 256 + threadIdx.x;
  int c = idx & cmask;
  float v = sc[c] * X[idx] + sh[c];
  if (res) v += res[idx];
  if (relu) v = fmaxf(v, 0.f);
  out[idx] = v;
}

__global__ __launch_bounds__(256) void transpose_k(const float* __restrict__ tok,
                                                   float* __restrict__ out) {
  int idx = blockIdx.x * 256 + threadIdx.x;               // (B, C=512, L) output order
  int l = idx & 1023, e = (idx >> 10) & 511, b = idx >> 19;
  out[idx] = tok[((size_t)b * L_ + l) * DM_ + e];
}

// ---------------- launcher ----------------
extern "C" void kernel_launch(void* const* d_in, const int* in_sizes, int n_in,
                              void* d_out, int out_size, void* d_ws, size_t ws_size,
                              hipStream_t stream) {
  const float* img      = (const float*)d_in[0];
  const float* conv1_w  = (const float*)d_in[1];
  const float* bn1_g    = (const float*)d_in[2];
  const float* bn1_b    = (const float*)d_in[3];
  const float* conv2_w  = (const float*)d_in[4];
  const float* bn2_g    = (const float*)d_in[5];
  const float* bn2_b    = (const float*)d_in[6];
  const float* ds_w     = (const float*)d_in[7];
  const float* ds_g     = (const float*)d_in[8];
  const float* ds_b     = (const float*)d_in[9];
  const float* inproj_w = (const float*)d_in[10];
  const float* convw    = (const float*)d_in[11];
  const float* convb    = (const float*)d_in[12];
  const float* dt_bias  = (const float*)d_in[13];
  const float* A_log    = (const float*)d_in[14];
  const float* Dp       = (const float*)d_in[15];
  const float* norm_w   = (const float*)d_in[16];
  const float* outproj_w= (const float*)d_in[17];
  const float* bno_g    = (const float*)d_in[18];
  const float* bno_b    = (const float*)d_in[19];
  const float* ff_w1    = (const float*)d_in[20];
  const float* ff_b1    = (const float*)d_in[21];
  const float* ff1_g    = (const float*)d_in[22];
  const float* ff1_b    = (const float*)d_in[23];
  const float* ff_w2    = (const float*)d_in[24];
  const float* ff_b2    = (const float*)d_in[25];
  const float* ff2_g    = (const float*)d_in[26];
  const float* ff2_b    = (const float*)d_in[27];

  float* w = (float*)d_ws;
  float* stats = w + O_STATS;
  // stats layout
  float* st_bn1 = stats + 0;     // 32
  float* st_bn2 = stats + 32;    // 64
  float* st_img = stats + 96;    // 2
  float* s1 = stats + 128, *t1 = stats + 144;
  float* s2 = stats + 160, *t2 = stats + 192;
  float* sds = stats + 224, *tds = stats + 256;

  hipMemsetAsync(stats, 0, STATS_SZ * sizeof(float), stream);

  conv1_k<<<2048, 256, 0, stream>>>(img, conv1_w, w + O_CONV1);
  stats_chan_k<<<dim3(16, 8), 256, 0, stream>>>(w + O_CONV1, st_bn1, 16, 65536, 2);
  finalize_bn_k<<<1, 64, 0, stream>>>(st_bn1, bn1_g, bn1_b, s1, t1, 16, 1.f / 131072.f);
  apply_bn1_k<<<8192, 256, 0, stream>>>(w + O_CONV1, s1, t1);
  conv2_k<<<1024, 256, 0, stream>>>(w + O_CONV1, conv2_w, w + O_CONV2);
  stats_chan_k<<<dim3(32, 8), 256, 0, stream>>>(w + O_CONV2, st_bn2, 32, 16384, 2);
  finalize_bn_k<<<1, 64, 0, stream>>>(st_bn2, bn2_g, bn2_b, s2, t2, 32, 1.f / 32768.f);
  img_stats_k<<<128, 256, 0, stream>>>(img, st_img);
  ds_fin_k<<<1, 64, 0, stream>>>(st_img, ds_w, ds_g, ds_b, sds, tds);
  stem_fuse_k<<<4096, 256, 0, stream>>>(w + O_CONV2, img, s2, t2, sds, tds, w + O_TOKA);

  float* tokA = w + O_TOKA;
  float* tokB = w + O_TOKB;
  float* zx   = w + O_ZX;
  float* xbc  = w + O_XBC;
  float* dtA  = w + O_DT;
  float* dAA  = w + O_DA;
  float* y    = w + O_CONV1;   // reuse
  float* proj = w + O_CONV2;   // reuse
  float* ffh  = w + O_XBC;     // reuse (xbc dead after scan)
  float* ffo  = w + O_FFO;

  for (int i = 0; i < 2; ++i) {
    float* stb = stats + 288 + i * 8192;
    gemm_k<64, 64, 4, 4><<<dim3(35, 32), 256, 0, stream>>>(
        tokA, inproj_w + (size_t)i * EPROJ * DM_, nullptr, zx, 2048, EPROJ, DM_);
    dt_prep_k<<<128, 256, 0, stream>>>(zx, dt_bias + i * 16, A_log + i * 16, dtA, dAA);
    conv_silu_k<<<9216, 256, 0, stream>>>(zx, convw + i * CONVD * 4, convb + i * CONVD, xbc);
    scan_k<<<128, 256, 0, stream>>>(xbc, dtA, dAA, Dp + i * 16, y);
    rmsnorm_gate_k<<<2048, 256, 0, stream>>>(y, zx, norm_w + i * DI_);
    gemm_k<64, 64, 4, 4><<<dim3(8, 32), 256, 0, stream>>>(
        y, outproj_w + (size_t)i * DM_ * DI_, nullptr, proj, 2048, DM_, DI_);
    colstats_k<<<dim3(2, 16), 256, 0, stream>>>(proj, stb + 0, DM_, 2048);
    finalize_bn_k<<<2, 256, 0, stream>>>(stb + 0, bno_g + i * DM_, bno_b + i * DM_,
                                         stb + 1024, stb + 1536, DM_, 1.f / 2048.f);
    apply_bn_k<<<4096, 256, 0, stream>>>(proj, stb + 1024, stb + 1536, tokA, tokB,
                                         2048 * DM_, DM_ - 1, 0);
    gemm_k<64, 64, 4, 4><<<dim3(16, 32), 256, 0, stream>>>(
        tokB, ff_w1 + (size_t)i * FH_ * DM_, ff_b1 + i * FH_, ffh, 2048, FH_, DM_);
    colstats_k<<<dim3(4, 16), 256, 0, stream>>>(ffh, stb + 2048, FH_, 2048);
    finalize_bn_k<<<4, 256, 0, stream>>>(stb + 2048, ff1_g + i * FH_, ff1_b + i * FH_,
                                         stb + 4096, stb + 5120, FH_, 1.f / 2048.f);
    apply_bn_k<<<8192, 256, 0, stream>>>(ffh, stb + 4096, stb + 5120, nullptr, ffh,
                                         2048 * FH_, FH_ - 1, 1);
    gemm_k<64, 64, 4, 4><<<dim3(8, 32), 256, 0, stream>>>(
        ffh, ff_w2 + (size_t)i * DM_ * FH_, ff_b2 + i * DM_, ffo, 2048, DM_, FH_);
    colstats_k<<<dim3(2, 16), 256, 0, stream>>>(ffo, stb + 6144, DM_, 2048);
    finalize_bn_k<<<2, 256, 0, stream>>>(stb + 6144, ff2_g + i * DM_, ff2_b + i * DM_,
                                         stb + 7168, stb + 7680, DM_, 1.f / 2048.f);
    apply_bn_k<<<4096, 256, 0, stream>>>(ffo, stb + 7168, stb + 7680, tokB, tokA,
                                         2048 * DM_, DM_ - 1, 0);
  }
  transpose_k<<<4096, 256, 0, stream>>>(tokA, (float*)d_out);
}

// Round 3
// 1134.780 us; speedup vs baseline: 1.5768x; 1.5768x over previous
//
#include <hip/hip_runtime.h>
#include <cstddef>
#include <cstdint>

// ---------------- problem constants ----------------
static constexpr int BN_   = 2;     // batch
static constexpr int L_    = 1024;  // sequence length (W/4)
static constexpr int DM_   = 512;   // d_model
static constexpr int EPROJ = 2192;  // in_proj out dim
static constexpr int DI_   = 1024;  // d_inner
static constexpr int CONVD = 1152;  // conv dim
static constexpr int HN_   = 16;    // heads
static constexpr int FH_   = 1024;  // ff hidden

// workspace float offsets
static constexpr size_t O_CONV1 = 0;                       // 2,097,152  (reused as y)
static constexpr size_t O_CONV2 = 2097152;                 // 1,048,576  (reused as proj)
static constexpr size_t O_TOKA  = O_CONV2 + 1048576;       // 1,048,576
static constexpr size_t O_TOKB  = O_TOKA + 1048576;        // 1,048,576
static constexpr size_t O_ZX    = O_TOKB + 1048576;        // 4,489,216
static constexpr size_t O_XBC   = O_ZX + 4489216;          // 2,359,296  (reused as ffh)
static constexpr size_t O_DT    = O_XBC + 2359296;         // 32,768
static constexpr size_t O_DA    = O_DT + 32768;            // 32,768
static constexpr size_t O_FFO   = O_DA + 32768;            // 1,048,576 (reused as scan Hbuf: 8*2*16*4096 = 1,048,576 exactly)
static constexpr size_t O_STATS = O_FFO + 1048576;         // 16,672
static constexpr size_t STATS_SZ = 16672;
static constexpr size_t O_APROD = O_STATS + STATS_SZ;      // 256 (scan chunk dA-products)

__device__ __forceinline__ float sigm(float x) { return 1.f / (1.f + expf(-x)); }

typedef __attribute__((ext_vector_type(8))) short short8;
typedef __attribute__((ext_vector_type(4))) float f32x4;

__device__ __forceinline__ short f2bf(float f) {
  union { float f; uint32_t u; } v; v.f = f;
  uint32_t u = v.u;
  uint32_t r = (u + 0x7fffu + ((u >> 16) & 1u)) >> 16;   // round-to-nearest-even
  return (short)r;
}

// ---------------- conv stem ----------------
__global__ __launch_bounds__(256) void conv1_k(const float* __restrict__ img,
                                               const float* __restrict__ w,
                                               float* __restrict__ out) {
  int idx = blockIdx.x * 256 + threadIdx.x;               // 524288 threads, 4 outputs each
  int xq = idx & 511, y = (idx >> 9) & 31, c = (idx >> 14) & 15, b = idx >> 18;
  __shared__ float ws[49];
  if (threadIdx.x < 49) ws[threadIdx.x] = w[c * 49 + threadIdx.x];
  __syncthreads();
  int x0 = xq * 4;
  int ix0 = 2 * x0 - 3;
  float acc[4] = {0.f, 0.f, 0.f, 0.f};
  for (int ky = 0; ky < 7; ++ky) {
    int iy = 2 * y - 3 + ky;
    if ((unsigned)iy >= 64u) continue;
    const float* irow = img + ((size_t)b * 64 + iy) * 4096;
    float in[13];
#pragma unroll
    for (int t = 0; t < 13; ++t) {
      int ix = ix0 + t;
      in[t] = ((unsigned)ix < 4096u) ? irow[ix] : 0.f;
    }
#pragma unroll
    for (int kx = 0; kx < 7; ++kx) {
      float wv = ws[ky * 7 + kx];
#pragma unroll
      for (int j = 0; j < 4; ++j) acc[j] += in[2 * j + kx] * wv;
    }
  }
  float4 o; o.x = acc[0]; o.y = acc[1]; o.z = acc[2]; o.w = acc[3];
  *reinterpret_cast<float4*>(&out[(size_t)idx * 4]) = o;
}

__global__ __launch_bounds__(256) void conv2_k(const float* __restrict__ inp,
                                               const float* __restrict__ w,
                                               float* __restrict__ out) {
  int idx = blockIdx.x * 256 + threadIdx.x;               // 262144 threads, 4 outputs each
  int xq = idx & 255, y = (idx >> 8) & 15, c2 = (idx >> 12) & 31, b = idx >> 17;
  __shared__ float ws[784];
  for (int t = threadIdx.x; t < 784; t += 256) ws[t] = w[c2 * 784 + t];
  __syncthreads();
  int x0 = xq * 4;
  int ix0 = 2 * x0 - 3;
  float acc[4] = {0.f, 0.f, 0.f, 0.f};
  for (int c1 = 0; c1 < 16; ++c1) {
    const float* ch = inp + ((size_t)(b * 16 + c1) * 32) * 2048;
    for (int ky = 0; ky < 7; ++ky) {
      int iy = 2 * y - 3 + ky;
      if ((unsigned)iy >= 32u) continue;
      const float* irow = ch + (size_t)iy * 2048;
      float in[13];
#pragma unroll
      for (int t = 0; t < 13; ++t) {
        int ix = ix0 + t;
        in[t] = ((unsigned)ix < 2048u) ? irow[ix] : 0.f;
      }
#pragma unroll
      for (int kx = 0; kx < 7; ++kx) {
        float wv = ws[c1 * 49 + ky * 7 + kx];
#pragma unroll
        for (int j = 0; j < 4; ++j) acc[j] += in[2 * j + kx] * wv;
      }
    }
  }
  float4 o; o.x = acc[0]; o.y = acc[1]; o.z = acc[2]; o.w = acc[3];
  *reinterpret_cast<float4*>(&out[(size_t)idx * 4]) = o;
}

// per-channel stats for [B][C][S] tensor -> atomicAdd into sums[c], sums[C+c]
__global__ __launch_bounds__(256) void stats_chan_k(const float* __restrict__ X,
                                                    float* __restrict__ sums,
                                                    int C, int S, int Bc) {
  int c = blockIdx.x, tid = threadIdx.x;
  float s = 0.f, q = 0.f;
  for (int b = 0; b < Bc; ++b) {
    const float* base = X + ((size_t)b * C + c) * S;
    for (int i = blockIdx.y * 256 + tid; i < S; i += gridDim.y * 256) {
      float v = base[i]; s += v; q += v * v;
    }
  }
  for (int o = 32; o > 0; o >>= 1) { s += __shfl_down(s, o); q += __shfl_down(q, o); }
  __shared__ float rs[4], rq[4];
  if ((tid & 63) == 0) { rs[tid >> 6] = s; rq[tid >> 6] = q; }
  __syncthreads();
  if (tid == 0) {
    atomicAdd(&sums[c], rs[0] + rs[1] + rs[2] + rs[3]);
    atomicAdd(&sums[C + c], rq[0] + rq[1] + rq[2] + rq[3]);
  }
}

__global__ void finalize_bn_k(const float* __restrict__ sums, const float* __restrict__ g,
                              const float* __restrict__ b, float* __restrict__ sc,
                              float* __restrict__ sh, int C, float inv) {
  int c = blockIdx.x * blockDim.x + threadIdx.x;
  if (c >= C) return;
  float mean = sums[c] * inv;
  float var = sums[C + c] * inv - mean * mean;
  float s = g[c] * rsqrtf(var + 1e-5f);
  sc[c] = s; sh[c] = b[c] - mean * s;
}

__global__ __launch_bounds__(256) void apply_bn1_k(float* __restrict__ x,
                                                   const float* __restrict__ sc,
                                                   const float* __restrict__ sh) {
  int idx = blockIdx.x * 256 + threadIdx.x;
  int c = (idx >> 16) & 15;                               // 32*2048 = 65536 per channel
  x[idx] = sc[c] * x[idx] + sh[c];
}

__global__ __launch_bounds__(256) void img_stats_k(const float* __restrict__ img,
                                                   float* __restrict__ sums) {
  int idx = blockIdx.x * 256 + threadIdx.x;               // 32768 samples
  int xx = idx & 1023, yy = (idx >> 10) & 15, b = idx >> 14;
  float v = img[((size_t)b * 64 + yy * 4) * 4096 + xx * 4];
  float s = v, q = v * v;
  for (int o = 32; o > 0; o >>= 1) { s += __shfl_down(s, o); q += __shfl_down(q, o); }
  __shared__ float rs[4], rq[4];
  if ((threadIdx.x & 63) == 0) { rs[threadIdx.x >> 6] = s; rq[threadIdx.x >> 6] = q; }
  __syncthreads();
  if (threadIdx.x == 0) {
    atomicAdd(&sums[0], rs[0] + rs[1] + rs[2] + rs[3]);
    atomicAdd(&sums[1], rq[0] + rq[1] + rq[2] + rq[3]);
  }
}

__global__ void ds_fin_k(const float* __restrict__ sums, const float* __restrict__ dsw,
                         const float* __restrict__ g, const float* __restrict__ b,
                         float* __restrict__ sc, float* __restrict__ sh) {
  int c = threadIdx.x;
  if (c >= 32) return;
  float m = sums[0] * (1.f / 32768.f);
  float var = sums[1] * (1.f / 32768.f) - m * m;
  float wv = dsw[c];
  float s = g[c] * rsqrtf(wv * wv * var + 1e-5f);
  sc[c] = wv * s; sh[c] = b[c] - wv * m * s;
}

// h = relu(bn2(conv2) + bn_ds(ds)); write tokens in (B, L, C) layout
__global__ __launch_bounds__(256) void stem_fuse_k(const float* __restrict__ conv2,
                                                   const float* __restrict__ img,
                                                   const float* __restrict__ s2, const float* __restrict__ t2,
                                                   const float* __restrict__ sds, const float* __restrict__ tds,
                                                   float* __restrict__ tok) {
  int idx = blockIdx.x * 256 + threadIdx.x;               // 2*1024*512
  int d = idx & 511, l = (idx >> 9) & 1023, b = idx >> 19;
  int c = d >> 4, hh = d & 15;
  float v = s2[c] * conv2[((size_t)(b * 32 + c) * 16 + hh) * 1024 + l] + t2[c]
          + sds[c] * img[((size_t)b * 64 + hh * 4) * 4096 + l * 4] + tds[c];
  tok[idx] = fmaxf(v, 0.f);
}

// -------- MFMA GEMM: Out(MxN f32) = A(MxK f32) @ W(NxK f32)^T (+bias), bf16 internally --------
// 128x128 tile, BK=32, 4 waves (2x2), each wave 64x64 = 4x4 frags of 16x16x32.
__global__ __launch_bounds__(256) void gemm_mfma_k(const float* __restrict__ A,
                                                   const float* __restrict__ W,
                                                   const float* __restrict__ bias,
                                                   float* __restrict__ Out,
                                                   int M, int N, int K) {
  // LDS: row stride 40 shorts (80B) -> 2-way bank aliasing only (free)
  __shared__ short As[128 * 40];
  __shared__ short Bs[128 * 40];
  const int tid = threadIdx.x;
  const int bm = blockIdx.y * 128;
  const int bn = blockIdx.x * 128;
  const int wave = tid >> 6;
  const int lane = tid & 63;
  const int wrow = (wave >> 1) * 64;
  const int wcol = (wave & 1) * 64;
  const int lr = lane >> 4;      // k-group (input frags) / row-group (output)
  const int lc = lane & 15;      // M-row (A) / N-col (B, D)

  // staging decomposition: thread -> (row 0..127, half 0..1), 16 floats each
  const int srow = tid >> 1;
  const int shalf = tid & 1;
  const float* aRow = A + (size_t)(bm + srow) * K + shalf * 16;
  const int wr = bn + srow;
  const bool wvalid = wr < N;
  const float* wRow = W + (size_t)(wvalid ? wr : 0) * K + shalf * 16;
  short* dstA = &As[srow * 40 + shalf * 16];
  short* dstB = &Bs[srow * 40 + shalf * 16];

  f32x4 acc[4][4];
#pragma unroll
  for (int i = 0; i < 4; ++i)
#pragma unroll
    for (int j = 0; j < 4; ++j) acc[i][j] = (f32x4){0.f, 0.f, 0.f, 0.f};

  for (int k0 = 0; k0 < K; k0 += 32) {
    float4 a0 = *reinterpret_cast<const float4*>(aRow + k0 + 0);
    float4 a1 = *reinterpret_cast<const float4*>(aRow + k0 + 4);
    float4 a2 = *reinterpret_cast<const float4*>(aRow + k0 + 8);
    float4 a3 = *reinterpret_cast<const float4*>(aRow + k0 + 12);
    float4 b0 = *reinterpret_cast<const float4*>(wRow + k0 + 0);
    float4 b1 = *reinterpret_cast<const float4*>(wRow + k0 + 4);
    float4 b2 = *reinterpret_cast<const float4*>(wRow + k0 + 8);
    float4 b3 = *reinterpret_cast<const float4*>(wRow + k0 + 12);
    if (!wvalid) { b0 = b1 = b2 = b3 = make_float4(0.f, 0.f, 0.f, 0.f); }
    short8 sa0, sa1, sb0, sb1;
    sa0[0] = f2bf(a0.x); sa0[1] = f2bf(a0.y); sa0[2] = f2bf(a0.z); sa0[3] = f2bf(a0.w);
    sa0[4] = f2bf(a1.x); sa0[5] = f2bf(a1.y); sa0[6] = f2bf(a1.z); sa0[7] = f2bf(a1.w);
    sa1[0] = f2bf(a2.x); sa1[1] = f2bf(a2.y); sa1[2] = f2bf(a2.z); sa1[3] = f2bf(a2.w);
    sa1[4] = f2bf(a3.x); sa1[5] = f2bf(a3.y); sa1[6] = f2bf(a3.z); sa1[7] = f2bf(a3.w);
    sb0[0] = f2bf(b0.x); sb0[1] = f2bf(b0.y); sb0[2] = f2bf(b0.z); sb0[3] = f2bf(b0.w);
    sb0[4] = f2bf(b1.x); sb0[5] = f2bf(b1.y); sb0[6] = f2bf(b1.z); sb0[7] = f2bf(b1.w);
    sb1[0] = f2bf(b2.x); sb1[1] = f2bf(b2.y); sb1[2] = f2bf(b2.z); sb1[3] = f2bf(b2.w);
    sb1[4] = f2bf(b3.x); sb1[5] = f2bf(b3.y); sb1[6] = f2bf(b3.z); sb1[7] = f2bf(b3.w);
    __syncthreads();   // prior iter's frag reads complete before overwrite
    *reinterpret_cast<short8*>(dstA + 0) = sa0;
    *reinterpret_cast<short8*>(dstA + 8) = sa1;
    *reinterpret_cast<short8*>(dstB + 0) = sb0;
    *reinterpret_cast<short8*>(dstB + 8) = sb1;
    __syncthreads();   // writes visible
    short8 af[4], bf[4];
#pragma unroll
    for (int i = 0; i < 4; ++i)
      af[i] = *reinterpret_cast<short8*>(&As[(wrow + i * 16 + lc) * 40 + lr * 8]);
#pragma unroll
    for (int j = 0; j < 4; ++j)
      bf[j] = *reinterpret_cast<short8*>(&Bs[(wcol + j * 16 + lc) * 40 + lr * 8]);
#pragma unroll
    for (int i = 0; i < 4; ++i)
#pragma unroll
      for (int j = 0; j < 4; ++j)
        acc[i][j] = __builtin_amdgcn_mfma_f32_16x16x32_bf16(af[i], bf[j], acc[i][j], 0, 0, 0);
  }

  // epilogue: D col = lane&15, row = (lane>>4)*4 + reg  (m89-verified)
#pragma unroll
  for (int j = 0; j < 4; ++j) {
    int gc = bn + wcol + j * 16 + lc;
    if (gc >= N) continue;
    float bv = bias ? bias[gc] : 0.f;
#pragma unroll
    for (int i = 0; i < 4; ++i) {
      int gr = bm + wrow + i * 16 + lr * 4;
#pragma unroll
      for (int r = 0; r < 4; ++r)
        Out[(size_t)(gr + r) * N + gc] = acc[i][j][r] + bv;
    }
  }
}

// ---------------- mamba pieces ----------------
__global__ __launch_bounds__(256) void dt_prep_k(const float* __restrict__ zx,
                                                 const float* __restrict__ dtb,
                                                 const float* __restrict__ alog,
                                                 float* __restrict__ dtO, float* __restrict__ dAO) {
  int idx = blockIdx.x * 256 + threadIdx.x;               // 32768
  int h = idx & 15, row = idx >> 4;
  float raw = zx[(size_t)row * EPROJ + 2176 + h] + dtb[h];
  float dt = raw > 20.f ? raw : log1pf(expf(raw));
  dtO[idx] = dt;
  dAO[idx] = expf(dt * (-expf(alog[h])));
}

__global__ __launch_bounds__(256) void conv_silu_k(const float* __restrict__ zx,
                                                   const float* __restrict__ cw,
                                                   const float* __restrict__ cb,
                                                   float* __restrict__ out) {
  int idx = blockIdx.x * 256 + threadIdx.x;               // 2*1024*1152
  int c = idx % CONVD;
  int row = idx / CONVD;
  int l = row & 1023, bb = row >> 10;
  float acc = cb[c];
#pragma unroll
  for (int k = 0; k < 4; ++k) {
    int ll = l - 3 + k;
    if (ll >= 0) acc += zx[((size_t)(bb * 1024 + ll)) * EPROJ + 1024 + c] * cw[c * 4 + k];
  }
  out[idx] = acc * sigm(acc);
}

// -------- chunked selective scan --------
// h_t = dA_t h_{t-1} + dt_t x_t B_t^T  (linear in h => chunk-associative)
// NC=8 chunks of CL=128. Phase A (EMITY=0): local states from h=0 + prod(dA).
// Phase B: combine chunk states sequentially (8 steps). Phase C (EMITY=1): re-run
// chunks from correct incoming state, emit y.
// grid 1024 = (b, h, pg, c); threads (pl 0..15, nq 0..15) -> (p, 4 n's).
template <int EMITY>
__global__ __launch_bounds__(256) void scan_chunk_k(const float* __restrict__ xbc,
                                                    const float* __restrict__ dtA,
                                                    const float* __restrict__ dAA,
                                                    const float* __restrict__ Dq,
                                                    float* __restrict__ Hbuf,
                                                    float* __restrict__ aprod,
                                                    float* __restrict__ y) {
  constexpr int SCH = 16;
  int bid = blockIdx.x;
  int c  = bid & 7;
  int pg = (bid >> 3) & 3;
  int hh = (bid >> 5) & 15;
  int b  = bid >> 9;
  int tid = threadIdx.x;
  int pl = tid >> 4, nq = tid & 15, n0 = nq * 4;
  int p = pg * 16 + pl;
  __shared__ float sB[2][SCH][64], sC[2][SCH][64], sx[2][SCH][16];
  __shared__ float sdt[2][SCH], sdA[2][SCH];
  const float* xb = xbc + (size_t)b * L_ * CONVD;
  const float* dtp = dtA + b * (L_ * HN_) + hh;
  const float* dAp = dAA + b * (L_ * HN_) + hh;
  float* yp_ = y + (size_t)b * L_ * DI_ + hh * 64 + p;
  float Dh = Dq[hh];
  size_t hoff = (((size_t)c * 2 + b) * 16 + hh) * 4096 + (size_t)p * 64 + n0;

  float4 st = make_float4(0.f, 0.f, 0.f, 0.f);
  if (EMITY) st = *reinterpret_cast<const float4*>(&Hbuf[hoff]);
  float ap = 1.f;

  auto stage = [&](int l0, int buf) {
    int ll = tid >> 4, nn = (tid & 15) * 4;
    const float* base = xb + (size_t)(l0 + ll) * CONVD;
    *reinterpret_cast<float4*>(&sB[buf][ll][nn]) = *reinterpret_cast<const float4*>(base + 1024 + nn);
    if (EMITY)
      *reinterpret_cast<float4*>(&sC[buf][ll][nn]) = *reinterpret_cast<const float4*>(base + 1088 + nn);
    if (nq < 4) {
      *reinterpret_cast<float4*>(&sx[buf][ll][nq * 4]) =
          *reinterpret_cast<const float4*>(base + hh * 64 + pg * 16 + nq * 4);
    } else if (nq == 4) {
      sdt[buf][ll] = dtp[(l0 + ll) * HN_];
    } else if (nq == 5) {
      sdA[buf][ll] = dAp[(l0 + ll) * HN_];
    }
  };

  int lbase = c * 128;
  stage(lbase, 0);
  int buf = 0;
  for (int s = 0; s < 8; ++s) {
    __syncthreads();
    if (s + 1 < 8) stage(lbase + (s + 1) * SCH, buf ^ 1);
#pragma unroll
    for (int j = 0; j < SCH; ++j) {
      float xv = sx[buf][j][pl];
      float dtv = sdt[buf][j], dAv = sdA[buf][j];
      float4 Bv = *reinterpret_cast<float4*>(&sB[buf][j][n0]);
      float co = dtv * xv;
      st.x = dAv * st.x + co * Bv.x;
      st.y = dAv * st.y + co * Bv.y;
      st.z = dAv * st.z + co * Bv.z;
      st.w = dAv * st.w + co * Bv.w;
      if (EMITY) {
        float4 Cv = *reinterpret_cast<float4*>(&sC[buf][j][n0]);
        float yv = st.x * Cv.x + st.y * Cv.y + st.z * Cv.z + st.w * Cv.w;
        yv += __shfl_xor(yv, 1);
        yv += __shfl_xor(yv, 2);
        yv += __shfl_xor(yv, 4);
        yv += __shfl_xor(yv, 8);
        if (nq == 0) yp_[(size_t)(lbase + s * SCH + j) * DI_] = yv + Dh * xv;
      } else {
        ap *= dAv;
      }
    }
    buf ^= 1;
  }
  if (!EMITY) {
    *reinterpret_cast<float4*>(&Hbuf[hoff]) = st;
    if (tid == 0) aprod[c * 32 + b * 16 + hh] = ap;
  }
}

// Phase B: Hbuf[c] (local end states) -> Hbuf[c] = incoming state for chunk c.
__global__ __launch_bounds__(256) void scan_comb_k(float* __restrict__ Hbuf,
                                                   const float* __restrict__ aprod) {
  int idx = blockIdx.x * 256 + threadIdx.x;               // 32768 = (b,h,p,n4)
  int n0 = (idx & 15) * 4;
  int p = (idx >> 4) & 63;
  int hh = (idx >> 10) & 15;
  int b = idx >> 14;
  size_t base = ((size_t)b * 16 + hh) * 4096 + (size_t)p * 64 + n0;
  float4 g = make_float4(0.f, 0.f, 0.f, 0.f);
#pragma unroll
  for (int c = 0; c < 8; ++c) {
    size_t off = (size_t)c * 131072 + base;
    float4 he = *reinterpret_cast<float4*>(&Hbuf[off]);
    float a = aprod[c * 32 + b * 16 + hh];
    *reinterpret_cast<float4*>(&Hbuf[off]) = g;
    g.x = a * g.x + he.x;
    g.y = a * g.y + he.y;
    g.z = a * g.z + he.z;
    g.w = a * g.w + he.w;
  }
}

// gated RMSNorm, in-place on y; z is cols [0,1024) of zxbcdt
__global__ __launch_bounds__(256) void rmsnorm_gate_k(float* __restrict__ y,
                                                      const float* __restrict__ zx,
                                                      const float* __restrict__ nw) {
  int row = blockIdx.x;
  float* yr = y + (size_t)row * DI_;
  const float* zr = zx + (size_t)row * EPROJ;
  int d0 = threadIdx.x * 4;
  float4 yv = *reinterpret_cast<float4*>(&yr[d0]);
  float4 zv = *reinterpret_cast<const float4*>(&zr[d0]);
  float4 g;
  g.x = yv.x * (zv.x * sigm(zv.x));
  g.y = yv.y * (zv.y * sigm(zv.y));
  g.z = yv.z * (zv.z * sigm(zv.z));
  g.w = yv.w * (zv.w * sigm(zv.w));
  float ss = g.x * g.x + g.y * g.y + g.z * g.z + g.w * g.w;
  for (int o = 32; o > 0; o >>= 1) ss += __shfl_down(ss, o);
  __shared__ float r4[4];
  __shared__ float tot;
  if ((threadIdx.x & 63) == 0) r4[threadIdx.x >> 6] = ss;
  __syncthreads();
  if (threadIdx.x == 0) tot = r4[0] + r4[1] + r4[2] + r4[3];
  __syncthreads();
  float rr = rsqrtf(tot * (1.f / DI_) + 1e-5f);
  float4 nwv = *reinterpret_cast<const float4*>(&nw[d0]);
  float4 o;
  o.x = g.x * rr * nwv.x; o.y = g.y * rr * nwv.y;
  o.z = g.z * rr * nwv.z; o.w = g.w * rr * nwv.w;
  *reinterpret_cast<float4*>(&yr[d0]) = o;
}

// column (per-channel) stats for row-major (rows x C)
__global__ __launch_bounds__(256) void colstats_k(const float* __restrict__ X,
                                                  float* __restrict__ sums, int C, int rows) {
  int c = blockIdx.x * 256 + threadIdx.x;
  int per = rows / gridDim.y;
  int r0 = blockIdx.y * per, r1 = r0 + per;
  float s = 0.f, q = 0.f;
  for (int r = r0; r < r1; ++r) { float v = X[(size_t)r * C + c]; s += v; q += v * v; }
  atomicAdd(&sums[c], s);
  atomicAdd(&sums[C + c], q);
}

__global__ __launch_bounds__(256) void apply_bn_k(const float* __restrict__ X,
                                                  const float* __restrict__ sc,
                                                  const float* __restrict__ sh,
                                                  const float* __restrict__ res,
                                                  float* __restrict__ out,
                                                  int n, int cmask, int relu) {
  int idx = blockIdx.x * 256 + threadIdx.x;
  int c = idx & cmask;
  float v = sc[c] * X[idx] + sh[c];
  if (res) v += res[idx];
  if (relu) v = fmaxf(v, 0.f);
  out[idx] = v;
}

__global__ __launch_bounds__(256) void transpose_k(const float* __restrict__ tok,
                                                   float* __restrict__ out) {
  int idx = blockIdx.x * 256 + threadIdx.x;               // (B, C=512, L) output order
  int l = idx & 1023, e = (idx >> 10) & 511, b = idx >> 19;
  out[idx] = tok[((size_t)b * L_ + l) * DM_ + e];
}

// ---------------- launcher ----------------
extern "C" void kernel_launch(void* const* d_in, const int* in_sizes, int n_in,
                              void* d_out, int out_size, void* d_ws, size_t ws_size,
                              hipStream_t stream) {
  const float* img      = (const float*)d_in[0];
  const float* conv1_w  = (const float*)d_in[1];
  const float* bn1_g    = (const float*)d_in[2];
  const float* bn1_b    = (const float*)d_in[3];
  const float* conv2_w  = (const float*)d_in[4];
  const float* bn2_g    = (const float*)d_in[5];
  const float* bn2_b    = (const float*)d_in[6];
  const float* ds_w     = (const float*)d_in[7];
  const float* ds_g     = (const float*)d_in[8];
  const float* ds_b     = (const float*)d_in[9];
  const float* inproj_w = (const float*)d_in[10];
  const float* convw    = (const float*)d_in[11];
  const float* convb    = (const float*)d_in[12];
  const float* dt_bias  = (const float*)d_in[13];
  const float* A_log    = (const float*)d_in[14];
  const float* Dp       = (const float*)d_in[15];
  const float* norm_w   = (const float*)d_in[16];
  const float* outproj_w= (const float*)d_in[17];
  const float* bno_g    = (const float*)d_in[18];
  const float* bno_b    = (const float*)d_in[19];
  const float* ff_w1    = (const float*)d_in[20];
  const float* ff_b1    = (const float*)d_in[21];
  const float* ff1_g    = (const float*)d_in[22];
  const float* ff1_b    = (const float*)d_in[23];
  const float* ff_w2    = (const float*)d_in[24];
  const float* ff_b2    = (const float*)d_in[25];
  const float* ff2_g    = (const float*)d_in[26];
  const float* ff2_b    = (const float*)d_in[27];

  float* w = (float*)d_ws;
  float* stats = w + O_STATS;
  float* st_bn1 = stats + 0;     // 32
  float* st_bn2 = stats + 32;    // 64
  float* st_img = stats + 96;    // 2
  float* s1 = stats + 128, *t1 = stats + 144;
  float* s2 = stats + 160, *t2 = stats + 192;
  float* sds = stats + 224, *tds = stats + 256;
  float* aprodp = w + O_APROD;

  hipMemsetAsync(stats, 0, STATS_SZ * sizeof(float), stream);

  conv1_k<<<2048, 256, 0, stream>>>(img, conv1_w, w + O_CONV1);
  stats_chan_k<<<dim3(16, 8), 256, 0, stream>>>(w + O_CONV1, st_bn1, 16, 65536, 2);
  finalize_bn_k<<<1, 64, 0, stream>>>(st_bn1, bn1_g, bn1_b, s1, t1, 16, 1.f / 131072.f);
  apply_bn1_k<<<8192, 256, 0, stream>>>(w + O_CONV1, s1, t1);
  conv2_k<<<1024, 256, 0, stream>>>(w + O_CONV1, conv2_w, w + O_CONV2);
  stats_chan_k<<<dim3(32, 8), 256, 0, stream>>>(w + O_CONV2, st_bn2, 32, 16384, 2);
  finalize_bn_k<<<1, 64, 0, stream>>>(st_bn2, bn2_g, bn2_b, s2, t2, 32, 1.f / 32768.f);
  img_stats_k<<<128, 256, 0, stream>>>(img, st_img);
  ds_fin_k<<<1, 64, 0, stream>>>(st_img, ds_w, ds_g, ds_b, sds, tds);
  stem_fuse_k<<<4096, 256, 0, stream>>>(w + O_CONV2, img, s2, t2, sds, tds, w + O_TOKA);

  float* tokA = w + O_TOKA;
  float* tokB = w + O_TOKB;
  float* zx   = w + O_ZX;
  float* xbc  = w + O_XBC;
  float* dtA  = w + O_DT;
  float* dAA  = w + O_DA;
  float* y    = w + O_CONV1;   // reuse
  float* proj = w + O_CONV2;   // reuse
  float* ffh  = w + O_XBC;     // reuse (xbc dead after scan)
  float* ffo  = w + O_FFO;     // also reused as scan Hbuf (dead outside FF tail)
  float* Hbuf = w + O_FFO;

  for (int i = 0; i < 2; ++i) {
    float* stb = stats + 288 + i * 8192;
    gemm_mfma_k<<<dim3(18, 16), 256, 0, stream>>>(
        tokA, inproj_w + (size_t)i * EPROJ * DM_, nullptr, zx, 2048, EPROJ, DM_);
    dt_prep_k<<<128, 256, 0, stream>>>(zx, dt_bias + i * 16, A_log + i * 16, dtA, dAA);
    conv_silu_k<<<9216, 256, 0, stream>>>(zx, convw + i * CONVD * 4, convb + i * CONVD, xbc);
    scan_chunk_k<0><<<1024, 256, 0, stream>>>(xbc, dtA, dAA, Dp + i * 16, Hbuf, aprodp, y);
    scan_comb_k<<<128, 256, 0, stream>>>(Hbuf, aprodp);
    scan_chunk_k<1><<<1024, 256, 0, stream>>>(xbc, dtA, dAA, Dp + i * 16, Hbuf, aprodp, y);
    rmsnorm_gate_k<<<2048, 256, 0, stream>>>(y, zx, norm_w + i * DI_);
    gemm_mfma_k<<<dim3(4, 16), 256, 0, stream>>>(
        y, outproj_w + (size_t)i * DM_ * DI_, nullptr, proj, 2048, DM_, DI_);
    colstats_k<<<dim3(2, 16), 256, 0, stream>>>(proj, stb + 0, DM_, 2048);
    finalize_bn_k<<<2, 256, 0, stream>>>(stb + 0, bno_g + i * DM_, bno_b + i * DM_,
                                         stb + 1024, stb + 1536, DM_, 1.f / 2048.f);
    apply_bn_k<<<4096, 256, 0, stream>>>(proj, stb + 1024, stb + 1536, tokA, tokB,
                                         2048 * DM_, DM_ - 1, 0);
    gemm_mfma_k<<<dim3(8, 16), 256, 0, stream>>>(
        tokB, ff_w1 + (size_t)i * FH_ * DM_, ff_b1 + i * FH_, ffh, 2048, FH_, DM_);
    colstats_k<<<dim3(4, 16), 256, 0, stream>>>(ffh, stb + 2048, FH_, 2048);
    finalize_bn_k<<<4, 256, 0, stream>>>(stb + 2048, ff1_g + i * FH_, ff1_b + i * FH_,
                                         stb + 4096, stb + 5120, FH_, 1.f / 2048.f);
    apply_bn_k<<<8192, 256, 0, stream>>>(ffh, stb + 4096, stb + 5120, nullptr, ffh,
                                         2048 * FH_, FH_ - 1, 1);
    gemm_mfma_k<<<dim3(4, 16), 256, 0, stream>>>(
        ffh, ff_w2 + (size_t)i * DM_ * FH_, ff_b2 + i * DM_, ffo, 2048, DM_, FH_);
    colstats_k<<<dim3(2, 16), 256, 0, stream>>>(ffo, stb + 6144, DM_, 2048);
    finalize_bn_k<<<2, 256, 0, stream>>>(stb + 6144, ff2_g + i * DM_, ff2_b + i * DM_,
                                         stb + 7168, stb + 7680, DM_, 1.f / 2048.f);
    apply_bn_k<<<4096, 256, 0, stream>>>(ffo, stb + 7168, stb + 7680, tokB, tokA,
                                         2048 * DM_, DM_ - 1, 0);
  }
  transpose_k<<<4096, 256, 0, stream>>>(tokA, (float*)d_out);
}

// Round 4
// 931.762 us; speedup vs baseline: 1.9204x; 1.2179x over previous
//
#include <hip/hip_runtime.h>
#include <cstddef>
#include <cstdint>

// ---------------- problem constants ----------------
static constexpr int BN_   = 2;     // batch
static constexpr int L_    = 1024;  // sequence length (W/4)
static constexpr int DM_   = 512;   // d_model
static constexpr int EPROJ = 2192;  // in_proj out dim
static constexpr int DI_   = 1024;  // d_inner
static constexpr int CONVD = 1152;  // conv dim
static constexpr int HN_   = 16;    // heads
static constexpr int FH_   = 1024;  // ff hidden

// workspace float offsets
static constexpr size_t O_CONV1 = 0;                       // 2,097,152  (reused as y)
static constexpr size_t O_CONV2 = 2097152;                 // 1,048,576  (reused as proj)
static constexpr size_t O_TOKA  = O_CONV2 + 1048576;       // 1,048,576
static constexpr size_t O_TOKB  = O_TOKA + 1048576;        // 1,048,576
static constexpr size_t O_ZX    = O_TOKB + 1048576;        // 4,489,216
static constexpr size_t O_XBC   = O_ZX + 4489216;          // 2,359,296  (reused as ffh)
static constexpr size_t O_DT    = O_XBC + 2359296;         // 32,768
static constexpr size_t O_DA    = O_DT + 32768;            // 32,768
static constexpr size_t O_FFO   = O_DA + 32768;            // 1,048,576 (reused as scan Hbuf)
static constexpr size_t O_STATS = O_FFO + 1048576;         // 16,672
static constexpr size_t STATS_SZ = 16672;
static constexpr size_t O_APROD = O_STATS + STATS_SZ;      // 256 (scan chunk dA-products)

__device__ __forceinline__ float sigm(float x) { return 1.f / (1.f + expf(-x)); }

typedef __attribute__((ext_vector_type(8))) short short8;
typedef __attribute__((ext_vector_type(4))) float f32x4;

__device__ __forceinline__ short f2bf(float f) {
  union { float f; uint32_t u; } v; v.f = f;
  uint32_t u = v.u;
  uint32_t r = (u + 0x7fffu + ((u >> 16) & 1u)) >> 16;   // round-to-nearest-even
  return (short)r;
}

// ---------------- conv stem ----------------
__global__ __launch_bounds__(256) void conv1_k(const float* __restrict__ img,
                                               const float* __restrict__ w,
                                               float* __restrict__ out) {
  int idx = blockIdx.x * 256 + threadIdx.x;               // 524288 threads, 4 outputs each
  int xq = idx & 511, y = (idx >> 9) & 31, c = (idx >> 14) & 15, b = idx >> 18;
  __shared__ float ws[49];
  if (threadIdx.x < 49) ws[threadIdx.x] = w[c * 49 + threadIdx.x];
  __syncthreads();
  int x0 = xq * 4;
  int ix0 = 2 * x0 - 3;
  float acc[4] = {0.f, 0.f, 0.f, 0.f};
  for (int ky = 0; ky < 7; ++ky) {
    int iy = 2 * y - 3 + ky;
    if ((unsigned)iy >= 64u) continue;
    const float* irow = img + ((size_t)b * 64 + iy) * 4096;
    float in[13];
#pragma unroll
    for (int t = 0; t < 13; ++t) {
      int ix = ix0 + t;
      in[t] = ((unsigned)ix < 4096u) ? irow[ix] : 0.f;
    }
#pragma unroll
    for (int kx = 0; kx < 7; ++kx) {
      float wv = ws[ky * 7 + kx];
#pragma unroll
      for (int j = 0; j < 4; ++j) acc[j] += in[2 * j + kx] * wv;
    }
  }
  float4 o; o.x = acc[0]; o.y = acc[1]; o.z = acc[2]; o.w = acc[3];
  *reinterpret_cast<float4*>(&out[(size_t)idx * 4]) = o;
}

// conv2 v2: block = (b, y, x-tile 256, c2-group of 8). Weights transposed in LDS
// ([c1][ky][kx][8c2], broadcast reads); input in registers; 8 outputs/thread.
__global__ __launch_bounds__(256) void conv2_k(const float* __restrict__ inp,
                                               const float* __restrict__ w,
                                               float* __restrict__ out) {
  __shared__ float wT[784 * 8];           // 25 KB
  int bid = blockIdx.x;                   // 512 blocks
  int c2g = bid & 3, xt = (bid >> 2) & 3, y = (bid >> 4) & 15, b = bid >> 8;
  int tid = threadIdx.x;
  for (int t = tid; t < 6272; t += 256) {
    int c2j = t & 7, tap = t >> 3;
    wT[t] = w[(size_t)(c2g * 8 + c2j) * 784 + tap];
  }
  __syncthreads();
  int ox = xt * 256 + tid;
  int ix0 = 2 * ox - 3;
  float acc[8] = {0.f, 0.f, 0.f, 0.f, 0.f, 0.f, 0.f, 0.f};
  for (int c1 = 0; c1 < 16; ++c1) {
    const float* ch = inp + ((size_t)(b * 16 + c1) * 32) * 2048;
#pragma unroll
    for (int ky = 0; ky < 7; ++ky) {
      int iy = 2 * y - 3 + ky;
      if ((unsigned)iy >= 32u) continue;
      const float* irow = ch + (size_t)iy * 2048;
      float in[7];
#pragma unroll
      for (int t = 0; t < 7; ++t) {
        int ix = ix0 + t;
        in[t] = ((unsigned)ix < 2048u) ? irow[ix] : 0.f;
      }
      const float* wrow = &wT[(c1 * 49 + ky * 7) * 8];
#pragma unroll
      for (int kx = 0; kx < 7; ++kx) {
        float4 w0 = *reinterpret_cast<const float4*>(wrow + kx * 8);
        float4 w1 = *reinterpret_cast<const float4*>(wrow + kx * 8 + 4);
        float iv = in[kx];
        acc[0] += iv * w0.x; acc[1] += iv * w0.y; acc[2] += iv * w0.z; acc[3] += iv * w0.w;
        acc[4] += iv * w1.x; acc[5] += iv * w1.y; acc[6] += iv * w1.z; acc[7] += iv * w1.w;
      }
    }
  }
  size_t obase = ((size_t)(b * 32 + c2g * 8) * 16 + y) * 1024 + ox;
#pragma unroll
  for (int j = 0; j < 8; ++j)
    out[obase + (size_t)j * 16384] = acc[j];
}

// per-channel stats for [B][C][S] tensor -> atomicAdd into sums[c], sums[C+c]
__global__ __launch_bounds__(256) void stats_chan_k(const float* __restrict__ X,
                                                    float* __restrict__ sums,
                                                    int C, int S, int Bc) {
  int c = blockIdx.x, tid = threadIdx.x;
  float s = 0.f, q = 0.f;
  for (int b = 0; b < Bc; ++b) {
    const float* base = X + ((size_t)b * C + c) * S;
    for (int i = blockIdx.y * 256 + tid; i < S; i += gridDim.y * 256) {
      float v = base[i]; s += v; q += v * v;
    }
  }
  for (int o = 32; o > 0; o >>= 1) { s += __shfl_down(s, o); q += __shfl_down(q, o); }
  __shared__ float rs[4], rq[4];
  if ((tid & 63) == 0) { rs[tid >> 6] = s; rq[tid >> 6] = q; }
  __syncthreads();
  if (tid == 0) {
    atomicAdd(&sums[c], rs[0] + rs[1] + rs[2] + rs[3]);
    atomicAdd(&sums[C + c], rq[0] + rq[1] + rq[2] + rq[3]);
  }
}

__global__ void finalize_bn_k(const float* __restrict__ sums, const float* __restrict__ g,
                              const float* __restrict__ b, float* __restrict__ sc,
                              float* __restrict__ sh, int C, float inv) {
  int c = blockIdx.x * blockDim.x + threadIdx.x;
  if (c >= C) return;
  float mean = sums[c] * inv;
  float var = sums[C + c] * inv - mean * mean;
  float s = g[c] * rsqrtf(var + 1e-5f);
  sc[c] = s; sh[c] = b[c] - mean * s;
}

__global__ __launch_bounds__(256) void apply_bn1_k(float* __restrict__ x,
                                                   const float* __restrict__ sc,
                                                   const float* __restrict__ sh) {
  int idx = blockIdx.x * 256 + threadIdx.x;
  int c = (idx >> 16) & 15;                               // 32*2048 = 65536 per channel
  x[idx] = sc[c] * x[idx] + sh[c];
}

__global__ __launch_bounds__(256) void img_stats_k(const float* __restrict__ img,
                                                   float* __restrict__ sums) {
  int idx = blockIdx.x * 256 + threadIdx.x;               // 32768 samples
  int xx = idx & 1023, yy = (idx >> 10) & 15, b = idx >> 14;
  float v = img[((size_t)b * 64 + yy * 4) * 4096 + xx * 4];
  float s = v, q = v * v;
  for (int o = 32; o > 0; o >>= 1) { s += __shfl_down(s, o); q += __shfl_down(q, o); }
  __shared__ float rs[4], rq[4];
  if ((threadIdx.x & 63) == 0) { rs[threadIdx.x >> 6] = s; rq[threadIdx.x >> 6] = q; }
  __syncthreads();
  if (threadIdx.x == 0) {
    atomicAdd(&sums[0], rs[0] + rs[1] + rs[2] + rs[3]);
    atomicAdd(&sums[1], rq[0] + rq[1] + rq[2] + rq[3]);
  }
}

__global__ void ds_fin_k(const float* __restrict__ sums, const float* __restrict__ dsw,
                         const float* __restrict__ g, const float* __restrict__ b,
                         float* __restrict__ sc, float* __restrict__ sh) {
  int c = threadIdx.x;
  if (c >= 32) return;
  float m = sums[0] * (1.f / 32768.f);
  float var = sums[1] * (1.f / 32768.f) - m * m;
  float wv = dsw[c];
  float s = g[c] * rsqrtf(wv * wv * var + 1e-5f);
  sc[c] = wv * s; sh[c] = b[c] - wv * m * s;
}

// h = relu(bn2(conv2) + bn_ds(ds)); write tokens in (B, L, C) layout
__global__ __launch_bounds__(256) void stem_fuse_k(const float* __restrict__ conv2,
                                                   const float* __restrict__ img,
                                                   const float* __restrict__ s2, const float* __restrict__ t2,
                                                   const float* __restrict__ sds, const float* __restrict__ tds,
                                                   float* __restrict__ tok) {
  int idx = blockIdx.x * 256 + threadIdx.x;               // 2*1024*512
  int d = idx & 511, l = (idx >> 9) & 1023, b = idx >> 19;
  int c = d >> 4, hh = d & 15;
  float v = s2[c] * conv2[((size_t)(b * 32 + c) * 16 + hh) * 1024 + l] + t2[c]
          + sds[c] * img[((size_t)b * 64 + hh * 4) * 4096 + l * 4] + tds[c];
  tok[idx] = fmaxf(v, 0.f);
}

// -------- MFMA GEMM: Out(MxN f32) = A(MxK f32) @ W(NxK f32)^T (+bias), bf16 internally --------
__global__ __launch_bounds__(256) void gemm_mfma_k(const float* __restrict__ A,
                                                   const float* __restrict__ W,
                                                   const float* __restrict__ bias,
                                                   float* __restrict__ Out,
                                                   int M, int N, int K) {
  __shared__ short As[128 * 40];
  __shared__ short Bs[128 * 40];
  const int tid = threadIdx.x;
  const int bm = blockIdx.y * 128;
  const int bn = blockIdx.x * 128;
  const int wave = tid >> 6;
  const int lane = tid & 63;
  const int wrow = (wave >> 1) * 64;
  const int wcol = (wave & 1) * 64;
  const int lr = lane >> 4;
  const int lc = lane & 15;

  const int srow = tid >> 1;
  const int shalf = tid & 1;
  const float* aRow = A + (size_t)(bm + srow) * K + shalf * 16;
  const int wr = bn + srow;
  const bool wvalid = wr < N;
  const float* wRow = W + (size_t)(wvalid ? wr : 0) * K + shalf * 16;
  short* dstA = &As[srow * 40 + shalf * 16];
  short* dstB = &Bs[srow * 40 + shalf * 16];

  f32x4 acc[4][4];
#pragma unroll
  for (int i = 0; i < 4; ++i)
#pragma unroll
    for (int j = 0; j < 4; ++j) acc[i][j] = (f32x4){0.f, 0.f, 0.f, 0.f};

  for (int k0 = 0; k0 < K; k0 += 32) {
    float4 a0 = *reinterpret_cast<const float4*>(aRow + k0 + 0);
    float4 a1 = *reinterpret_cast<const float4*>(aRow + k0 + 4);
    float4 a2 = *reinterpret_cast<const float4*>(aRow + k0 + 8);
    float4 a3 = *reinterpret_cast<const float4*>(aRow + k0 + 12);
    float4 b0 = *reinterpret_cast<const float4*>(wRow + k0 + 0);
    float4 b1 = *reinterpret_cast<const float4*>(wRow + k0 + 4);
    float4 b2 = *reinterpret_cast<const float4*>(wRow + k0 + 8);
    float4 b3 = *reinterpret_cast<const float4*>(wRow + k0 + 12);
    if (!wvalid) { b0 = b1 = b2 = b3 = make_float4(0.f, 0.f, 0.f, 0.f); }
    short8 sa0, sa1, sb0, sb1;
    sa0[0] = f2bf(a0.x); sa0[1] = f2bf(a0.y); sa0[2] = f2bf(a0.z); sa0[3] = f2bf(a0.w);
    sa0[4] = f2bf(a1.x); sa0[5] = f2bf(a1.y); sa0[6] = f2bf(a1.z); sa0[7] = f2bf(a1.w);
    sa1[0] = f2bf(a2.x); sa1[1] = f2bf(a2.y); sa1[2] = f2bf(a2.z); sa1[3] = f2bf(a2.w);
    sa1[4] = f2bf(a3.x); sa1[5] = f2bf(a3.y); sa1[6] = f2bf(a3.z); sa1[7] = f2bf(a3.w);
    sb0[0] = f2bf(b0.x); sb0[1] = f2bf(b0.y); sb0[2] = f2bf(b0.z); sb0[3] = f2bf(b0.w);
    sb0[4] = f2bf(b1.x); sb0[5] = f2bf(b1.y); sb0[6] = f2bf(b1.z); sb0[7] = f2bf(b1.w);
    sb1[0] = f2bf(b2.x); sb1[1] = f2bf(b2.y); sb1[2] = f2bf(b2.z); sb1[3] = f2bf(b2.w);
    sb1[4] = f2bf(b3.x); sb1[5] = f2bf(b3.y); sb1[6] = f2bf(b3.z); sb1[7] = f2bf(b3.w);
    __syncthreads();
    *reinterpret_cast<short8*>(dstA + 0) = sa0;
    *reinterpret_cast<short8*>(dstA + 8) = sa1;
    *reinterpret_cast<short8*>(dstB + 0) = sb0;
    *reinterpret_cast<short8*>(dstB + 8) = sb1;
    __syncthreads();
    short8 af[4], bf[4];
#pragma unroll
    for (int i = 0; i < 4; ++i)
      af[i] = *reinterpret_cast<short8*>(&As[(wrow + i * 16 + lc) * 40 + lr * 8]);
#pragma unroll
    for (int j = 0; j < 4; ++j)
      bf[j] = *reinterpret_cast<short8*>(&Bs[(wcol + j * 16 + lc) * 40 + lr * 8]);
#pragma unroll
    for (int i = 0; i < 4; ++i)
#pragma unroll
      for (int j = 0; j < 4; ++j)
        acc[i][j] = __builtin_amdgcn_mfma_f32_16x16x32_bf16(af[i], bf[j], acc[i][j], 0, 0, 0);
  }

#pragma unroll
  for (int j = 0; j < 4; ++j) {
    int gc = bn + wcol + j * 16 + lc;
    if (gc >= N) continue;
    float bv = bias ? bias[gc] : 0.f;
#pragma unroll
    for (int i = 0; i < 4; ++i) {
      int gr = bm + wrow + i * 16 + lr * 4;
#pragma unroll
      for (int r = 0; r < 4; ++r)
        Out[(size_t)(gr + r) * N + gc] = acc[i][j][r] + bv;
    }
  }
}

// ---------------- mamba pieces ----------------
__global__ __launch_bounds__(256) void dt_prep_k(const float* __restrict__ zx,
                                                 const float* __restrict__ dtb,
                                                 const float* __restrict__ alog,
                                                 float* __restrict__ dtO, float* __restrict__ dAO) {
  int idx = blockIdx.x * 256 + threadIdx.x;               // 32768
  int h = idx & 15, row = idx >> 4;
  float raw = zx[(size_t)row * EPROJ + 2176 + h] + dtb[h];
  float dt = raw > 20.f ? raw : log1pf(expf(raw));
  dtO[idx] = dt;
  dAO[idx] = expf(dt * (-expf(alog[h])));
}

__global__ __launch_bounds__(256) void conv_silu_k(const float* __restrict__ zx,
                                                   const float* __restrict__ cw,
                                                   const float* __restrict__ cb,
                                                   float* __restrict__ out) {
  int idx = blockIdx.x * 256 + threadIdx.x;               // 2*1024*1152
  int c = idx % CONVD;
  int row = idx / CONVD;
  int l = row & 1023, bb = row >> 10;
  float acc = cb[c];
#pragma unroll
  for (int k = 0; k < 4; ++k) {
    int ll = l - 3 + k;
    if (ll >= 0) acc += zx[((size_t)(bb * 1024 + ll)) * EPROJ + 1024 + c] * cw[c * 4 + k];
  }
  out[idx] = acc * sigm(acc);
}

// -------- chunked selective scan --------
template <int EMITY>
__global__ __launch_bounds__(256) void scan_chunk_k(const float* __restrict__ xbc,
                                                    const float* __restrict__ dtA,
                                                    const float* __restrict__ dAA,
                                                    const float* __restrict__ Dq,
                                                    float* __restrict__ Hbuf,
                                                    float* __restrict__ aprod,
                                                    float* __restrict__ y) {
  constexpr int SCH = 16;
  int bid = blockIdx.x;
  int c  = bid & 7;
  int pg = (bid >> 3) & 3;
  int hh = (bid >> 5) & 15;
  int b  = bid >> 9;
  int tid = threadIdx.x;
  int pl = tid >> 4, nq = tid & 15, n0 = nq * 4;
  int p = pg * 16 + pl;
  __shared__ float sB[2][SCH][64], sC[2][SCH][64], sx[2][SCH][16];
  __shared__ float sdt[2][SCH], sdA[2][SCH];
  const float* xb = xbc + (size_t)b * L_ * CONVD;
  const float* dtp = dtA + b * (L_ * HN_) + hh;
  const float* dAp = dAA + b * (L_ * HN_) + hh;
  float* yp_ = y + (size_t)b * L_ * DI_ + hh * 64 + p;
  float Dh = Dq[hh];
  size_t hoff = (((size_t)c * 2 + b) * 16 + hh) * 4096 + (size_t)p * 64 + n0;

  float4 st = make_float4(0.f, 0.f, 0.f, 0.f);
  if (EMITY) st = *reinterpret_cast<const float4*>(&Hbuf[hoff]);
  float ap = 1.f;

  auto stage = [&](int l0, int buf) {
    int ll = tid >> 4, nn = (tid & 15) * 4;
    const float* base = xb + (size_t)(l0 + ll) * CONVD;
    *reinterpret_cast<float4*>(&sB[buf][ll][nn]) = *reinterpret_cast<const float4*>(base + 1024 + nn);
    if (EMITY)
      *reinterpret_cast<float4*>(&sC[buf][ll][nn]) = *reinterpret_cast<const float4*>(base + 1088 + nn);
    if (nq < 4) {
      *reinterpret_cast<float4*>(&sx[buf][ll][nq * 4]) =
          *reinterpret_cast<const float4*>(base + hh * 64 + pg * 16 + nq * 4);
    } else if (nq == 4) {
      sdt[buf][ll] = dtp[(l0 + ll) * HN_];
    } else if (nq == 5) {
      sdA[buf][ll] = dAp[(l0 + ll) * HN_];
    }
  };

  int lbase = c * 128;
  stage(lbase, 0);
  int buf = 0;
  for (int s = 0; s < 8; ++s) {
    __syncthreads();
    if (s + 1 < 8) stage(lbase + (s + 1) * SCH, buf ^ 1);
#pragma unroll
    for (int j = 0; j < SCH; ++j) {
      float xv = sx[buf][j][pl];
      float dtv = sdt[buf][j], dAv = sdA[buf][j];
      float4 Bv = *reinterpret_cast<float4*>(&sB[buf][j][n0]);
      float co = dtv * xv;
      st.x = dAv * st.x + co * Bv.x;
      st.y = dAv * st.y + co * Bv.y;
      st.z = dAv * st.z + co * Bv.z;
      st.w = dAv * st.w + co * Bv.w;
      if (EMITY) {
        float4 Cv = *reinterpret_cast<float4*>(&sC[buf][j][n0]);
        float yv = st.x * Cv.x + st.y * Cv.y + st.z * Cv.z + st.w * Cv.w;
        yv += __shfl_xor(yv, 1);
        yv += __shfl_xor(yv, 2);
        yv += __shfl_xor(yv, 4);
        yv += __shfl_xor(yv, 8);
        if (nq == 0) yp_[(size_t)(lbase + s * SCH + j) * DI_] = yv + Dh * xv;
      } else {
        ap *= dAv;
      }
    }
    buf ^= 1;
  }
  if (!EMITY) {
    *reinterpret_cast<float4*>(&Hbuf[hoff]) = st;
    if (tid == 0) aprod[c * 32 + b * 16 + hh] = ap;
  }
}

// Phase B: Hbuf[c] (local end states) -> Hbuf[c] = incoming state for chunk c.
__global__ __launch_bounds__(256) void scan_comb_k(float* __restrict__ Hbuf,
                                                   const float* __restrict__ aprod) {
  int idx = blockIdx.x * 256 + threadIdx.x;               // 32768 = (b,h,p,n4)
  int n0 = (idx & 15) * 4;
  int p = (idx >> 4) & 63;
  int hh = (idx >> 10) & 15;
  int b = idx >> 14;
  size_t base = ((size_t)b * 16 + hh) * 4096 + (size_t)p * 64 + n0;
  float4 g = make_float4(0.f, 0.f, 0.f, 0.f);
#pragma unroll
  for (int c = 0; c < 8; ++c) {
    size_t off = (size_t)c * 131072 + base;
    float4 he = *reinterpret_cast<float4*>(&Hbuf[off]);
    float a = aprod[c * 32 + b * 16 + hh];
    *reinterpret_cast<float4*>(&Hbuf[off]) = g;
    g.x = a * g.x + he.x;
    g.y = a * g.y + he.y;
    g.z = a * g.z + he.z;
    g.w = a * g.w + he.w;
  }
}

// gated RMSNorm, in-place on y; z is cols [0,1024) of zxbcdt
__global__ __launch_bounds__(256) void rmsnorm_gate_k(float* __restrict__ y,
                                                      const float* __restrict__ zx,
                                                      const float* __restrict__ nw) {
  int row = blockIdx.x;
  float* yr = y + (size_t)row * DI_;
  const float* zr = zx + (size_t)row * EPROJ;
  int d0 = threadIdx.x * 4;
  float4 yv = *reinterpret_cast<float4*>(&yr[d0]);
  float4 zv = *reinterpret_cast<const float4*>(&zr[d0]);
  float4 g;
  g.x = yv.x * (zv.x * sigm(zv.x));
  g.y = yv.y * (zv.y * sigm(zv.y));
  g.z = yv.z * (zv.z * sigm(zv.z));
  g.w = yv.w * (zv.w * sigm(zv.w));
  float ss = g.x * g.x + g.y * g.y + g.z * g.z + g.w * g.w;
  for (int o = 32; o > 0; o >>= 1) ss += __shfl_down(ss, o);
  __shared__ float r4[4];
  __shared__ float tot;
  if ((threadIdx.x & 63) == 0) r4[threadIdx.x >> 6] = ss;
  __syncthreads();
  if (threadIdx.x == 0) tot = r4[0] + r4[1] + r4[2] + r4[3];
  __syncthreads();
  float rr = rsqrtf(tot * (1.f / DI_) + 1e-5f);
  float4 nwv = *reinterpret_cast<const float4*>(&nw[d0]);
  float4 o;
  o.x = g.x * rr * nwv.x; o.y = g.y * rr * nwv.y;
  o.z = g.z * rr * nwv.z; o.w = g.w * rr * nwv.w;
  *reinterpret_cast<float4*>(&yr[d0]) = o;
}

// column (per-channel) stats for row-major (rows x C)
__global__ __launch_bounds__(256) void colstats_k(const float* __restrict__ X,
                                                  float* __restrict__ sums, int C, int rows) {
  int c = blockIdx.x * 256 + threadIdx.x;
  int per = rows / gridDim.y;
  int r0 = blockIdx.y * per, r1 = r0 + per;
  float s = 0.f, q = 0.f;
  for (int r = r0; r < r1; ++r) { float v = X[(size_t)r * C + c]; s += v; q += v * v; }
  atomicAdd(&sums[c], s);
  atomicAdd(&sums[C + c], q);
}

__global__ __launch_bounds__(256) void apply_bn_k(const float* __restrict__ X,
                                                  const float* __restrict__ sc,
                                                  const float* __restrict__ sh,
                                                  const float* __restrict__ res,
                                                  float* __restrict__ out,
                                                  int n, int cmask, int relu) {
  int idx = blockIdx.x * 256 + threadIdx.x;
  int c = idx & cmask;
  float v = sc[c] * X[idx] + sh[c];
  if (res) v += res[idx];
  if (relu) v = fmaxf(v, 0.f);
  out[idx] = v;
}

// LDS-tiled transpose: out[b][e][l] = tok[b][l][e]
__global__ __launch_bounds__(256) void transpose_k(const float* __restrict__ tok,
                                                   float* __restrict__ out) {
  __shared__ float tile[32][33];
  int bid = blockIdx.x;                                   // 1024 = 2b * 32lb * 16eb
  int eb = bid & 15, lb = (bid >> 4) & 31, b = bid >> 9;
  int tx = threadIdx.x & 31, ty = threadIdx.x >> 5;
#pragma unroll
  for (int i = 0; i < 4; ++i) {
    int l = lb * 32 + ty + i * 8;
    tile[ty + i * 8][tx] = tok[((size_t)b * 1024 + l) * 512 + eb * 32 + tx];
  }
  __syncthreads();
#pragma unroll
  for (int i = 0; i < 4; ++i) {
    int e = eb * 32 + ty + i * 8;
    out[((size_t)b * 512 + e) * 1024 + lb * 32 + tx] = tile[tx][ty + i * 8];
  }
}

// ---------------- launcher ----------------
extern "C" void kernel_launch(void* const* d_in, const int* in_sizes, int n_in,
                              void* d_out, int out_size, void* d_ws, size_t ws_size,
                              hipStream_t stream) {
  const float* img      = (const float*)d_in[0];
  const float* conv1_w  = (const float*)d_in[1];
  const float* bn1_g    = (const float*)d_in[2];
  const float* bn1_b    = (const float*)d_in[3];
  const float* conv2_w  = (const float*)d_in[4];
  const float* bn2_g    = (const float*)d_in[5];
  const float* bn2_b    = (const float*)d_in[6];
  const float* ds_w     = (const float*)d_in[7];
  const float* ds_g     = (const float*)d_in[8];
  const float* ds_b     = (const float*)d_in[9];
  const float* inproj_w = (const float*)d_in[10];
  const float* convw    = (const float*)d_in[11];
  const float* convb    = (const float*)d_in[12];
  const float* dt_bias  = (const float*)d_in[13];
  const float* A_log    = (const float*)d_in[14];
  const float* Dp       = (const float*)d_in[15];
  const float* norm_w   = (const float*)d_in[16];
  const float* outproj_w= (const float*)d_in[17];
  const float* bno_g    = (const float*)d_in[18];
  const float* bno_b    = (const float*)d_in[19];
  const float* ff_w1    = (const float*)d_in[20];
  const float* ff_b1    = (const float*)d_in[21];
  const float* ff1_g    = (const float*)d_in[22];
  const float* ff1_b    = (const float*)d_in[23];
  const float* ff_w2    = (const float*)d_in[24];
  const float* ff_b2    = (const float*)d_in[25];
  const float* ff2_g    = (const float*)d_in[26];
  const float* ff2_b    = (const float*)d_in[27];

  float* w = (float*)d_ws;
  float* stats = w + O_STATS;
  float* st_bn1 = stats + 0;     // 32
  float* st_bn2 = stats + 32;    // 64
  float* st_img = stats + 96;    // 2
  float* s1 = stats + 128, *t1 = stats + 144;
  float* s2 = stats + 160, *t2 = stats + 192;
  float* sds = stats + 224, *tds = stats + 256;
  float* aprodp = w + O_APROD;

  hipMemsetAsync(stats, 0, STATS_SZ * sizeof(float), stream);

  conv1_k<<<2048, 256, 0, stream>>>(img, conv1_w, w + O_CONV1);
  stats_chan_k<<<dim3(16, 8), 256, 0, stream>>>(w + O_CONV1, st_bn1, 16, 65536, 2);
  finalize_bn_k<<<1, 64, 0, stream>>>(st_bn1, bn1_g, bn1_b, s1, t1, 16, 1.f / 131072.f);
  apply_bn1_k<<<8192, 256, 0, stream>>>(w + O_CONV1, s1, t1);
  conv2_k<<<512, 256, 0, stream>>>(w + O_CONV1, conv2_w, w + O_CONV2);
  stats_chan_k<<<dim3(32, 8), 256, 0, stream>>>(w + O_CONV2, st_bn2, 32, 16384, 2);
  finalize_bn_k<<<1, 64, 0, stream>>>(st_bn2, bn2_g, bn2_b, s2, t2, 32, 1.f / 32768.f);
  img_stats_k<<<128, 256, 0, stream>>>(img, st_img);
  ds_fin_k<<<1, 64, 0, stream>>>(st_img, ds_w, ds_g, ds_b, sds, tds);
  stem_fuse_k<<<4096, 256, 0, stream>>>(w + O_CONV2, img, s2, t2, sds, tds, w + O_TOKA);

  float* tokA = w + O_TOKA;
  float* tokB = w + O_TOKB;
  float* zx   = w + O_ZX;
  float* xbc  = w + O_XBC;
  float* dtA  = w + O_DT;
  float* dAA  = w + O_DA;
  float* y    = w + O_CONV1;   // reuse
  float* proj = w + O_CONV2;   // reuse
  float* ffh  = w + O_XBC;     // reuse (xbc dead after scan)
  float* ffo  = w + O_FFO;     // also reused as scan Hbuf
  float* Hbuf = w + O_FFO;

  for (int i = 0; i < 2; ++i) {
    float* stb = stats + 288 + i * 8192;
    gemm_mfma_k<<<dim3(18, 16), 256, 0, stream>>>(
        tokA, inproj_w + (size_t)i * EPROJ * DM_, nullptr, zx, 2048, EPROJ, DM_);
    dt_prep_k<<<128, 256, 0, stream>>>(zx, dt_bias + i * 16, A_log + i * 16, dtA, dAA);
    conv_silu_k<<<9216, 256, 0, stream>>>(zx, convw + i * CONVD * 4, convb + i * CONVD, xbc);
    scan_chunk_k<0><<<1024, 256, 0, stream>>>(xbc, dtA, dAA, Dp + i * 16, Hbuf, aprodp, y);
    scan_comb_k<<<128, 256, 0, stream>>>(Hbuf, aprodp);
    scan_chunk_k<1><<<1024, 256, 0, stream>>>(xbc, dtA, dAA, Dp + i * 16, Hbuf, aprodp, y);
    rmsnorm_gate_k<<<2048, 256, 0, stream>>>(y, zx, norm_w + i * DI_);
    gemm_mfma_k<<<dim3(4, 16), 256, 0, stream>>>(
        y, outproj_w + (size_t)i * DM_ * DI_, nullptr, proj, 2048, DM_, DI_);
    colstats_k<<<dim3(2, 16), 256, 0, stream>>>(proj, stb + 0, DM_, 2048);
    finalize_bn_k<<<2, 256, 0, stream>>>(stb + 0, bno_g + i * DM_, bno_b + i * DM_,
                                         stb + 1024, stb + 1536, DM_, 1.f / 2048.f);
    apply_bn_k<<<4096, 256, 0, stream>>>(proj, stb + 1024, stb + 1536, tokA, tokB,
                                         2048 * DM_, DM_ - 1, 0);
    gemm_mfma_k<<<dim3(8, 16), 256, 0, stream>>>(
        tokB, ff_w1 + (size_t)i * FH_ * DM_, ff_b1 + i * FH_, ffh, 2048, FH_, DM_);
    colstats_k<<<dim3(4, 16), 256, 0, stream>>>(ffh, stb + 2048, FH_, 2048);
    finalize_bn_k<<<4, 256, 0, stream>>>(stb + 2048, ff1_g + i * FH_, ff1_b + i * FH_,
                                         stb + 4096, stb + 5120, FH_, 1.f / 2048.f);
    apply_bn_k<<<8192, 256, 0, stream>>>(ffh, stb + 4096, stb + 5120, nullptr, ffh,
                                         2048 * FH_, FH_ - 1, 1);
    gemm_mfma_k<<<dim3(4, 16), 256, 0, stream>>>(
        ffh, ff_w2 + (size_t)i * DM_ * FH_, ff_b2 + i * DM_, ffo, 2048, DM_, FH_);
    colstats_k<<<dim3(2, 16), 256, 0, stream>>>(ffo, stb + 6144, DM_, 2048);
    finalize_bn_k<<<2, 256, 0, stream>>>(stb + 6144, ff2_g + i * DM_, ff2_b + i * DM_,
                                         stb + 7168, stb + 7680, DM_, 1.f / 2048.f);
    apply_bn_k<<<4096, 256, 0, stream>>>(ffo, stb + 7168, stb + 7680, tokB, tokA,
                                         2048 * DM_, DM_ - 1, 0);
  }
  transpose_k<<<1024, 256, 0, stream>>>(tokA, (float*)d_out);
}

// Round 5
// 726.778 us; speedup vs baseline: 2.4620x; 1.2820x over previous
//
#include <hip/hip_runtime.h>
#include <cstddef>
#include <cstdint>

// ---------------- problem constants ----------------
static constexpr int BN_   = 2;     // batch
static constexpr int L_    = 1024;  // sequence length (W/4)
static constexpr int DM_   = 512;   // d_model
static constexpr int EPROJ = 2192;  // in_proj out dim
static constexpr int DI_   = 1024;  // d_inner
static constexpr int CONVD = 1152;  // conv dim
static constexpr int HN_   = 16;    // heads
static constexpr int FH_   = 1024;  // ff hidden

// workspace float offsets
static constexpr size_t O_CONV1 = 0;                       // 2,097,152  (reused as y)
static constexpr size_t O_CONV2 = 2097152;                 // 1,048,576  (reused as proj)
static constexpr size_t O_TOKA  = O_CONV2 + 1048576;       // 1,048,576
static constexpr size_t O_TOKB  = O_TOKA + 1048576;        // 1,048,576
static constexpr size_t O_ZX    = O_TOKB + 1048576;        // 4,489,216
static constexpr size_t O_XBC   = O_ZX + 4489216;          // 2,359,296  (reused as ffh)
static constexpr size_t O_DT    = O_XBC + 2359296;         // 32,768
static constexpr size_t O_DA    = O_DT + 32768;            // 32,768
static constexpr size_t O_FFO   = O_DA + 32768;            // 1,048,576 (reused as scan Hbuf)
static constexpr size_t O_STATS = O_FFO + 1048576;         // 16,672
static constexpr size_t STATS_SZ = 16672;
static constexpr size_t O_APROD = O_STATS + STATS_SZ;      // 256
static constexpr size_t O_WB    = O_APROD + 256;           // 14,336 floats (bf16 conv2 weights 32x896)

__device__ __forceinline__ float sigm(float x) { return 1.f / (1.f + expf(-x)); }

typedef __attribute__((ext_vector_type(8))) short short8;
typedef __attribute__((ext_vector_type(4))) float f32x4;

__device__ __forceinline__ ushort f2bf(float f) {
  union { float f; uint32_t u; } v; v.f = f;
  uint32_t u = v.u;
  uint32_t r = (u + 0x7fffu + ((u >> 16) & 1u)) >> 16;   // round-to-nearest-even
  return (ushort)r;
}

// ---------------- conv stem ----------------
__global__ __launch_bounds__(256) void conv1_k(const float* __restrict__ img,
                                               const float* __restrict__ w,
                                               float* __restrict__ out) {
  int idx = blockIdx.x * 256 + threadIdx.x;               // 524288 threads, 4 outputs each
  int xq = idx & 511, y = (idx >> 9) & 31, c = (idx >> 14) & 15, b = idx >> 18;
  __shared__ float ws[49];
  if (threadIdx.x < 49) ws[threadIdx.x] = w[c * 49 + threadIdx.x];
  __syncthreads();
  int ix0 = 8 * xq - 3;
  bool fast = (xq > 0) && (xq < 511);
  float acc[4] = {0.f, 0.f, 0.f, 0.f};
  for (int ky = 0; ky < 7; ++ky) {
    int iy = 2 * y - 3 + ky;
    if ((unsigned)iy >= 64u) continue;
    const float* irow = img + ((size_t)b * 64 + iy) * 4096;
    float in[13];
    if (fast) {
      float4 f0 = *reinterpret_cast<const float4*>(&irow[ix0 - 1]);   // 16B aligned
      float4 f1 = *reinterpret_cast<const float4*>(&irow[ix0 + 3]);
      float4 f2 = *reinterpret_cast<const float4*>(&irow[ix0 + 7]);
      float4 f3 = *reinterpret_cast<const float4*>(&irow[ix0 + 11]);
      in[0] = f0.y; in[1] = f0.z; in[2] = f0.w;
      in[3] = f1.x; in[4] = f1.y; in[5] = f1.z; in[6] = f1.w;
      in[7] = f2.x; in[8] = f2.y; in[9] = f2.z; in[10] = f2.w;
      in[11] = f3.x; in[12] = f3.y;
    } else {
#pragma unroll
      for (int t = 0; t < 13; ++t) {
        int ix = ix0 + t;
        in[t] = ((unsigned)ix < 4096u) ? irow[ix] : 0.f;
      }
    }
#pragma unroll
    for (int kx = 0; kx < 7; ++kx) {
      float wv = ws[ky * 7 + kx];
#pragma unroll
      for (int j = 0; j < 4; ++j) acc[j] += in[2 * j + kx] * wv;
    }
  }
  float4 o; o.x = acc[0]; o.y = acc[1]; o.z = acc[2]; o.w = acc[3];
  *reinterpret_cast<float4*>(&out[(size_t)idx * 4]) = o;
}

// conv2 weight prep: w[32][16][7][7] f32 -> Wb[32][896] bf16, k = (c1*7+ky)*8+kx, kx padded to 8
__global__ __launch_bounds__(256) void wprep_k(const float* __restrict__ w,
                                               ushort* __restrict__ wb) {
  int idx = blockIdx.x * 256 + threadIdx.x;   // 28672
  int c2 = idx / 896, r = idx % 896;
  int p = r >> 3, kx = r & 7;
  int c1 = p / 7, ky = p - c1 * 7;
  float v = (kx < 7) ? w[((size_t)(c2 * 16 + c1) * 7 + ky) * 7 + kx] : 0.f;
  wb[idx] = f2bf(v);
}

// conv2 as implicit-GEMM MFMA. Block = 64 positions x 32 channels at fixed (b,y).
// bn1 (from raw sums) fused into A-staging. grid 512 = 2b*16y*16xt.
__global__ __launch_bounds__(256) void conv2_mfma_k(const float* __restrict__ conv1out,
                                                    const float* __restrict__ bn1sums,
                                                    const float* __restrict__ bn1g,
                                                    const float* __restrict__ bn1b,
                                                    const ushort* __restrict__ Wb,
                                                    float* __restrict__ out) {
  constexpr int RS = 160;                       // A row stride in bf16 elems
  __shared__ ushort Asub[4 * RS];
  __shared__ ushort Bsub[32 * 40];
  __shared__ float s1l[16], t1l[16];
  int bid = blockIdx.x;
  int xt = bid & 15, y = (bid >> 4) & 15, b = bid >> 8;
  int x0 = xt * 64;
  int tid = threadIdx.x;
  int wave = tid >> 6, lane = tid & 63;
  int lr = lane >> 4, lc = lane & 15;
  int sr = wave, si = tid & 63;                  // staging: wave sr owns A row sr
  if (tid < 16) {
    float mean = bn1sums[tid] * (1.f / 131072.f);
    float var = bn1sums[16 + tid] * (1.f / 131072.f) - mean * mean;
    float s = bn1g[tid] * rsqrtf(var + 1e-5f);
    s1l[tid] = s; t1l[tid] = bn1b[tid] - mean * s;
  }
  f32x4 acc[2];
  acc[0] = (f32x4){0.f, 0.f, 0.f, 0.f};
  acc[1] = (f32x4){0.f, 0.f, 0.f, 0.f};
  __syncthreads();

  float aval[3];
  uint2 bval;
  auto fetch = [&](int c) {
    bval = *reinterpret_cast<const uint2*>(&Wb[(tid >> 3) * 896 + c * 32 + (tid & 7) * 4]);
    int p = 4 * c + sr;
    int c1 = p / 7, ky = p - c1 * 7;
    int iy = 2 * y - 3 + ky;
    bool rowok = (unsigned)iy < 32u;
    const float* src = conv1out + (((size_t)(b * 16 + c1) * 32 + (rowok ? iy : 0)) * 2048);
    float s1 = s1l[c1], t1v = t1l[c1];
#pragma unroll
    for (int rep = 0; rep < 3; ++rep) {
      int i = si + rep * 64;
      int gx = 2 * x0 + i - 3;
      bool ok = rowok && (i < 134) && ((unsigned)gx < 2048u);
      float raw = src[ok ? gx : 0];
      aval[rep] = ok ? (s1 * raw + t1v) : 0.f;
    }
  };

  fetch(0);
  for (int c = 0; c < 28; ++c) {
    // store staged regs -> LDS
    *reinterpret_cast<uint2*>(&Bsub[(tid >> 3) * 40 + (tid & 7) * 4]) = bval;
#pragma unroll
    for (int rep = 0; rep < 3; ++rep) {
      int i = si + rep * 64;
      if (i < RS) Asub[sr * RS + i] = f2bf(aval[rep]);
    }
    __syncthreads();
    if (c + 1 < 28) fetch(c + 1);               // prefetch overlaps MFMA below
    int pos = wave * 16 + lc;
    union { uint32_t u[4]; short8 s; } ua;
    ua.u[0] = *reinterpret_cast<const uint32_t*>(&Asub[lr * RS + 2 * pos + 0]);
    ua.u[1] = *reinterpret_cast<const uint32_t*>(&Asub[lr * RS + 2 * pos + 2]);
    ua.u[2] = *reinterpret_cast<const uint32_t*>(&Asub[lr * RS + 2 * pos + 4]);
    ua.u[3] = *reinterpret_cast<const uint32_t*>(&Asub[lr * RS + 2 * pos + 6]);
    short8 af = ua.s;
    short8 bf0 = *reinterpret_cast<const short8*>(&Bsub[(0 + lc) * 40 + lr * 8]);
    short8 bf1 = *reinterpret_cast<const short8*>(&Bsub[(16 + lc) * 40 + lr * 8]);
    acc[0] = __builtin_amdgcn_mfma_f32_16x16x32_bf16(af, bf0, acc[0], 0, 0, 0);
    acc[1] = __builtin_amdgcn_mfma_f32_16x16x32_bf16(af, bf1, acc[1], 0, 0, 0);
    __syncthreads();
  }
#pragma unroll
  for (int j = 0; j < 2; ++j) {
    int c2 = j * 16 + lc;
    size_t base = (((size_t)(b * 32 + c2)) * 16 + y) * 1024 + x0 + wave * 16 + lr * 4;
#pragma unroll
    for (int r = 0; r < 4; ++r) out[base + r] = acc[j][r];
  }
}

// per-channel stats for [B][C][S] tensor -> atomicAdd into sums[c], sums[C+c]
__global__ __launch_bounds__(256) void stats_chan_k(const float* __restrict__ X,
                                                    float* __restrict__ sums,
                                                    int C, int S, int Bc) {
  int c = blockIdx.x, tid = threadIdx.x;
  float s = 0.f, q = 0.f;
  for (int b = 0; b < Bc; ++b) {
    const float* base = X + ((size_t)b * C + c) * S;
    for (int i = blockIdx.y * 256 + tid; i < S; i += gridDim.y * 256) {
      float v = base[i]; s += v; q += v * v;
    }
  }
  for (int o = 32; o > 0; o >>= 1) { s += __shfl_down(s, o); q += __shfl_down(q, o); }
  __shared__ float rs[4], rq[4];
  if ((tid & 63) == 0) { rs[tid >> 6] = s; rq[tid >> 6] = q; }
  __syncthreads();
  if (tid == 0) {
    atomicAdd(&sums[c], rs[0] + rs[1] + rs[2] + rs[3]);
    atomicAdd(&sums[C + c], rq[0] + rq[1] + rq[2] + rq[3]);
  }
}

__global__ __launch_bounds__(256) void img_stats_k(const float* __restrict__ img,
                                                   float* __restrict__ sums) {
  int idx = blockIdx.x * 256 + threadIdx.x;               // 32768 samples
  int xx = idx & 1023, yy = (idx >> 10) & 15, b = idx >> 14;
  float v = img[((size_t)b * 64 + yy * 4) * 4096 + xx * 4];
  float s = v, q = v * v;
  for (int o = 32; o > 0; o >>= 1) { s += __shfl_down(s, o); q += __shfl_down(q, o); }
  __shared__ float rs[4], rq[4];
  if ((threadIdx.x & 63) == 0) { rs[threadIdx.x >> 6] = s; rq[threadIdx.x >> 6] = q; }
  __syncthreads();
  if (threadIdx.x == 0) {
    atomicAdd(&sums[0], rs[0] + rs[1] + rs[2] + rs[3]);
    atomicAdd(&sums[1], rq[0] + rq[1] + rq[2] + rq[3]);
  }
}

// h = relu(bn2(conv2) + bn_ds(ds)); bn2/ds finalize fused. tokens (B,L,C).
__global__ __launch_bounds__(256) void stem_fuse_k(const float* __restrict__ conv2,
                                                   const float* __restrict__ img,
                                                   const float* __restrict__ bn2sums,
                                                   const float* __restrict__ g2, const float* __restrict__ b2,
                                                   const float* __restrict__ imgsums,
                                                   const float* __restrict__ dsw,
                                                   const float* __restrict__ dsg, const float* __restrict__ dsb,
                                                   float* __restrict__ tok) {
  int idx = blockIdx.x * 256 + threadIdx.x;               // 2*1024*512
  int d = idx & 511, l = (idx >> 9) & 1023, b = idx >> 19;
  int c = d >> 4, hh = d & 15;
  float m2 = bn2sums[c] * (1.f / 32768.f);
  float v2 = bn2sums[32 + c] * (1.f / 32768.f) - m2 * m2;
  float s2 = g2[c] * rsqrtf(v2 + 1e-5f);
  float mi = imgsums[0] * (1.f / 32768.f);
  float vi = imgsums[1] * (1.f / 32768.f) - mi * mi;
  float wv = dsw[c];
  float sd = dsg[c] * rsqrtf(wv * wv * vi + 1e-5f);
  float v = s2 * conv2[((size_t)(b * 32 + c) * 16 + hh) * 1024 + l] + (b2[c] - m2 * s2)
          + (wv * sd) * img[((size_t)b * 64 + hh * 4) * 4096 + l * 4] + (dsb[c] - wv * mi * sd);
  tok[idx] = fmaxf(v, 0.f);
}

// -------- MFMA GEMM: Out = A @ W^T (+bias), bf16 internally; optional fused col-stats --------
__global__ __launch_bounds__(256) void gemm_mfma_k(const float* __restrict__ A,
                                                   const float* __restrict__ W,
                                                   const float* __restrict__ bias,
                                                   float* __restrict__ Out,
                                                   float* __restrict__ colsums,
                                                   int M, int N, int K) {
  __shared__ short As[128 * 40];
  __shared__ short Bs[128 * 40];
  const int tid = threadIdx.x;
  const int bm = blockIdx.y * 128;
  const int bn = blockIdx.x * 128;
  const int wave = tid >> 6;
  const int lane = tid & 63;
  const int wrow = (wave >> 1) * 64;
  const int wcol = (wave & 1) * 64;
  const int lr = lane >> 4;
  const int lc = lane & 15;

  const int srow = tid >> 1;
  const int shalf = tid & 1;
  const float* aRow = A + (size_t)(bm + srow) * K + shalf * 16;
  const int wr = bn + srow;
  const bool wvalid = wr < N;
  const float* wRow = W + (size_t)(wvalid ? wr : 0) * K + shalf * 16;
  short* dstA = &As[srow * 40 + shalf * 16];
  short* dstB = &Bs[srow * 40 + shalf * 16];

  f32x4 acc[4][4];
#pragma unroll
  for (int i = 0; i < 4; ++i)
#pragma unroll
    for (int j = 0; j < 4; ++j) acc[i][j] = (f32x4){0.f, 0.f, 0.f, 0.f};

  for (int k0 = 0; k0 < K; k0 += 32) {
    float4 a0 = *reinterpret_cast<const float4*>(aRow + k0 + 0);
    float4 a1 = *reinterpret_cast<const float4*>(aRow + k0 + 4);
    float4 a2 = *reinterpret_cast<const float4*>(aRow + k0 + 8);
    float4 a3 = *reinterpret_cast<const float4*>(aRow + k0 + 12);
    float4 b0 = *reinterpret_cast<const float4*>(wRow + k0 + 0);
    float4 b1 = *reinterpret_cast<const float4*>(wRow + k0 + 4);
    float4 b2 = *reinterpret_cast<const float4*>(wRow + k0 + 8);
    float4 b3 = *reinterpret_cast<const float4*>(wRow + k0 + 12);
    if (!wvalid) { b0 = b1 = b2 = b3 = make_float4(0.f, 0.f, 0.f, 0.f); }
    short8 sa0, sa1, sb0, sb1;
    sa0[0] = f2bf(a0.x); sa0[1] = f2bf(a0.y); sa0[2] = f2bf(a0.z); sa0[3] = f2bf(a0.w);
    sa0[4] = f2bf(a1.x); sa0[5] = f2bf(a1.y); sa0[6] = f2bf(a1.z); sa0[7] = f2bf(a1.w);
    sa1[0] = f2bf(a2.x); sa1[1] = f2bf(a2.y); sa1[2] = f2bf(a2.z); sa1[3] = f2bf(a2.w);
    sa1[4] = f2bf(a3.x); sa1[5] = f2bf(a3.y); sa1[6] = f2bf(a3.z); sa1[7] = f2bf(a3.w);
    sb0[0] = f2bf(b0.x); sb0[1] = f2bf(b0.y); sb0[2] = f2bf(b0.z); sb0[3] = f2bf(b0.w);
    sb0[4] = f2bf(b1.x); sb0[5] = f2bf(b1.y); sb0[6] = f2bf(b1.z); sb0[7] = f2bf(b1.w);
    sb1[0] = f2bf(b2.x); sb1[1] = f2bf(b2.y); sb1[2] = f2bf(b2.z); sb1[3] = f2bf(b2.w);
    sb1[4] = f2bf(b3.x); sb1[5] = f2bf(b3.y); sb1[6] = f2bf(b3.z); sb1[7] = f2bf(b3.w);
    __syncthreads();
    *reinterpret_cast<short8*>(dstA + 0) = sa0;
    *reinterpret_cast<short8*>(dstA + 8) = sa1;
    *reinterpret_cast<short8*>(dstB + 0) = sb0;
    *reinterpret_cast<short8*>(dstB + 8) = sb1;
    __syncthreads();
    short8 af[4], bf[4];
#pragma unroll
    for (int i = 0; i < 4; ++i)
      af[i] = *reinterpret_cast<short8*>(&As[(wrow + i * 16 + lc) * 40 + lr * 8]);
#pragma unroll
    for (int j = 0; j < 4; ++j)
      bf[j] = *reinterpret_cast<short8*>(&Bs[(wcol + j * 16 + lc) * 40 + lr * 8]);
#pragma unroll
    for (int i = 0; i < 4; ++i)
#pragma unroll
      for (int j = 0; j < 4; ++j)
        acc[i][j] = __builtin_amdgcn_mfma_f32_16x16x32_bf16(af[i], bf[j], acc[i][j], 0, 0, 0);
  }

#pragma unroll
  for (int j = 0; j < 4; ++j) {
    int gc = bn + wcol + j * 16 + lc;
    if (gc >= N) continue;
    float bv = bias ? bias[gc] : 0.f;
    float cs = 0.f, cq = 0.f;
#pragma unroll
    for (int i = 0; i < 4; ++i) {
      int gr = bm + wrow + i * 16 + lr * 4;
#pragma unroll
      for (int r = 0; r < 4; ++r) {
        float o = acc[i][j][r] + bv;
        Out[(size_t)(gr + r) * N + gc] = o;
        cs += o; cq += o * o;
      }
    }
    if (colsums) {
      atomicAdd(&colsums[gc], cs);
      atomicAdd(&colsums[N + gc], cq);
    }
  }
}

// ---------------- mamba pieces ----------------
// depthwise causal conv + silu; dt softplus/dA prep fused into first 32768 threads
__global__ __launch_bounds__(256) void conv_silu_dt_k(const float* __restrict__ zx,
                                                      const float* __restrict__ cw,
                                                      const float* __restrict__ cb,
                                                      const float* __restrict__ dtb,
                                                      const float* __restrict__ alog,
                                                      float* __restrict__ out,
                                                      float* __restrict__ dtO,
                                                      float* __restrict__ dAO) {
  int idx = blockIdx.x * 256 + threadIdx.x;               // 2*1024*1152
  if (idx < 32768) {
    int h = idx & 15, row = idx >> 4;
    float raw = zx[(size_t)row * EPROJ + 2176 + h] + dtb[h];
    float dt = raw > 20.f ? raw : log1pf(expf(raw));
    dtO[idx] = dt;
    dAO[idx] = expf(dt * (-expf(alog[h])));
  }
  int c = idx % CONVD;
  int row = idx / CONVD;
  int l = row & 1023, bb = row >> 10;
  float acc = cb[c];
#pragma unroll
  for (int k = 0; k < 4; ++k) {
    int ll = l - 3 + k;
    if (ll >= 0) acc += zx[((size_t)(bb * 1024 + ll)) * EPROJ + 1024 + c] * cw[c * 4 + k];
  }
  out[idx] = acc * sigm(acc);
}

// -------- chunked selective scan --------
template <int EMITY>
__global__ __launch_bounds__(256) void scan_chunk_k(const float* __restrict__ xbc,
                                                    const float* __restrict__ dtA,
                                                    const float* __restrict__ dAA,
                                                    const float* __restrict__ Dq,
                                                    float* __restrict__ Hbuf,
                                                    float* __restrict__ aprod,
                                                    float* __restrict__ y) {
  constexpr int SCH = 16;
  int bid = blockIdx.x;
  int c  = bid & 7;
  int pg = (bid >> 3) & 3;
  int hh = (bid >> 5) & 15;
  int b  = bid >> 9;
  int tid = threadIdx.x;
  int pl = tid >> 4, nq = tid & 15, n0 = nq * 4;
  int p = pg * 16 + pl;
  __shared__ float sB[2][SCH][64], sC[2][SCH][64], sx[2][SCH][16];
  __shared__ float sdt[2][SCH], sdA[2][SCH];
  const float* xb = xbc + (size_t)b * L_ * CONVD;
  const float* dtp = dtA + b * (L_ * HN_) + hh;
  const float* dAp = dAA + b * (L_ * HN_) + hh;
  float* yp_ = y + (size_t)b * L_ * DI_ + hh * 64 + p;
  float Dh = Dq[hh];
  size_t hoff = (((size_t)c * 2 + b) * 16 + hh) * 4096 + (size_t)p * 64 + n0;

  float4 st = make_float4(0.f, 0.f, 0.f, 0.f);
  if (EMITY) st = *reinterpret_cast<const float4*>(&Hbuf[hoff]);
  float ap = 1.f;

  auto stage = [&](int l0, int buf) {
    int ll = tid >> 4, nn = (tid & 15) * 4;
    const float* base = xb + (size_t)(l0 + ll) * CONVD;
    *reinterpret_cast<float4*>(&sB[buf][ll][nn]) = *reinterpret_cast<const float4*>(base + 1024 + nn);
    if (EMITY)
      *reinterpret_cast<float4*>(&sC[buf][ll][nn]) = *reinterpret_cast<const float4*>(base + 1088 + nn);
    if (nq < 4) {
      *reinterpret_cast<float4*>(&sx[buf][ll][nq * 4]) =
          *reinterpret_cast<const float4*>(base + hh * 64 + pg * 16 + nq * 4);
    } else if (nq == 4) {
      sdt[buf][ll] = dtp[(l0 + ll) * HN_];
    } else if (nq == 5) {
      sdA[buf][ll] = dAp[(l0 + ll) * HN_];
    }
  };

  int lbase = c * 128;
  stage(lbase, 0);
  int buf = 0;
  for (int s = 0; s < 8; ++s) {
    __syncthreads();
    if (s + 1 < 8) stage(lbase + (s + 1) * SCH, buf ^ 1);
#pragma unroll
    for (int j = 0; j < SCH; ++j) {
      float xv = sx[buf][j][pl];
      float dtv = sdt[buf][j], dAv = sdA[buf][j];
      float4 Bv = *reinterpret_cast<float4*>(&sB[buf][j][n0]);
      float co = dtv * xv;
      st.x = dAv * st.x + co * Bv.x;
      st.y = dAv * st.y + co * Bv.y;
      st.z = dAv * st.z + co * Bv.z;
      st.w = dAv * st.w + co * Bv.w;
      if (EMITY) {
        float4 Cv = *reinterpret_cast<float4*>(&sC[buf][j][n0]);
        float yv = st.x * Cv.x + st.y * Cv.y + st.z * Cv.z + st.w * Cv.w;
        yv += __shfl_xor(yv, 1);
        yv += __shfl_xor(yv, 2);
        yv += __shfl_xor(yv, 4);
        yv += __shfl_xor(yv, 8);
        if (nq == 0) yp_[(size_t)(lbase + s * SCH + j) * DI_] = yv + Dh * xv;
      } else {
        ap *= dAv;
      }
    }
    buf ^= 1;
  }
  if (!EMITY) {
    *reinterpret_cast<float4*>(&Hbuf[hoff]) = st;
    if (tid == 0) aprod[c * 32 + b * 16 + hh] = ap;
  }
}

__global__ __launch_bounds__(256) void scan_comb_k(float* __restrict__ Hbuf,
                                                   const float* __restrict__ aprod) {
  int idx = blockIdx.x * 256 + threadIdx.x;               // 32768 = (b,h,p,n4)
  int n0 = (idx & 15) * 4;
  int p = (idx >> 4) & 63;
  int hh = (idx >> 10) & 15;
  int b = idx >> 14;
  size_t base = ((size_t)b * 16 + hh) * 4096 + (size_t)p * 64 + n0;
  float4 g = make_float4(0.f, 0.f, 0.f, 0.f);
#pragma unroll
  for (int c = 0; c < 8; ++c) {
    size_t off = (size_t)c * 131072 + base;
    float4 he = *reinterpret_cast<float4*>(&Hbuf[off]);
    float a = aprod[c * 32 + b * 16 + hh];
    *reinterpret_cast<float4*>(&Hbuf[off]) = g;
    g.x = a * g.x + he.x;
    g.y = a * g.y + he.y;
    g.z = a * g.z + he.z;
    g.w = a * g.w + he.w;
  }
}

// gated RMSNorm, in-place on y
__global__ __launch_bounds__(256) void rmsnorm_gate_k(float* __restrict__ y,
                                                      const float* __restrict__ zx,
                                                      const float* __restrict__ nw) {
  int row = blockIdx.x;
  float* yr = y + (size_t)row * DI_;
  const float* zr = zx + (size_t)row * EPROJ;
  int d0 = threadIdx.x * 4;
  float4 yv = *reinterpret_cast<float4*>(&yr[d0]);
  float4 zv = *reinterpret_cast<const float4*>(&zr[d0]);
  float4 g;
  g.x = yv.x * (zv.x * sigm(zv.x));
  g.y = yv.y * (zv.y * sigm(zv.y));
  g.z = yv.z * (zv.z * sigm(zv.z));
  g.w = yv.w * (zv.w * sigm(zv.w));
  float ss = g.x * g.x + g.y * g.y + g.z * g.z + g.w * g.w;
  for (int o = 32; o > 0; o >>= 1) ss += __shfl_down(ss, o);
  __shared__ float r4[4];
  __shared__ float tot;
  if ((threadIdx.x & 63) == 0) r4[threadIdx.x >> 6] = ss;
  __syncthreads();
  if (threadIdx.x == 0) tot = r4[0] + r4[1] + r4[2] + r4[3];
  __syncthreads();
  float rr = rsqrtf(tot * (1.f / DI_) + 1e-5f);
  float4 nwv = *reinterpret_cast<const float4*>(&nw[d0]);
  float4 o;
  o.x = g.x * rr * nwv.x; o.y = g.y * rr * nwv.y;
  o.z = g.z * rr * nwv.z; o.w = g.w * rr * nwv.w;
  *reinterpret_cast<float4*>(&yr[d0]) = o;
}

// BN apply with finalize fused (reads raw sums)
__global__ __launch_bounds__(256) void apply_bn_fin_k(const float* __restrict__ X,
                                                      const float* __restrict__ sums,
                                                      const float* __restrict__ g,
                                                      const float* __restrict__ bb,
                                                      const float* __restrict__ res,
                                                      float* __restrict__ out,
                                                      int cmask, int C, float inv, int relu) {
  int idx = blockIdx.x * 256 + threadIdx.x;
  int c = idx & cmask;
  float mean = sums[c] * inv;
  float var = sums[C + c] * inv - mean * mean;
  float s = g[c] * rsqrtf(var + 1e-5f);
  float v = s * X[idx] + (bb[c] - mean * s);
  if (res) v += res[idx];
  if (relu) v = fmaxf(v, 0.f);
  out[idx] = v;
}

// LDS-tiled transpose: out[b][e][l] = tok[b][l][e]
__global__ __launch_bounds__(256) void transpose_k(const float* __restrict__ tok,
                                                   float* __restrict__ out) {
  __shared__ float tile[32][33];
  int bid = blockIdx.x;                                   // 1024 = 2b * 32lb * 16eb
  int eb = bid & 15, lb = (bid >> 4) & 31, b = bid >> 9;
  int tx = threadIdx.x & 31, ty = threadIdx.x >> 5;
#pragma unroll
  for (int i = 0; i < 4; ++i) {
    int l = lb * 32 + ty + i * 8;
    tile[ty + i * 8][tx] = tok[((size_t)b * 1024 + l) * 512 + eb * 32 + tx];
  }
  __syncthreads();
#pragma unroll
  for (int i = 0; i < 4; ++i) {
    int e = eb * 32 + ty + i * 8;
    out[((size_t)b * 512 + e) * 1024 + lb * 32 + tx] = tile[tx][ty + i * 8];
  }
}

// ---------------- launcher ----------------
extern "C" void kernel_launch(void* const* d_in, const int* in_sizes, int n_in,
                              void* d_out, int out_size, void* d_ws, size_t ws_size,
                              hipStream_t stream) {
  const float* img      = (const float*)d_in[0];
  const float* conv1_w  = (const float*)d_in[1];
  const float* bn1_g    = (const float*)d_in[2];
  const float* bn1_b    = (const float*)d_in[3];
  const float* conv2_w  = (const float*)d_in[4];
  const float* bn2_g    = (const float*)d_in[5];
  const float* bn2_b    = (const float*)d_in[6];
  const float* ds_w     = (const float*)d_in[7];
  const float* ds_g     = (const float*)d_in[8];
  const float* ds_b     = (const float*)d_in[9];
  const float* inproj_w = (const float*)d_in[10];
  const float* convw    = (const float*)d_in[11];
  const float* convb    = (const float*)d_in[12];
  const float* dt_bias  = (const float*)d_in[13];
  const float* A_log    = (const float*)d_in[14];
  const float* Dp       = (const float*)d_in[15];
  const float* norm_w   = (const float*)d_in[16];
  const float* outproj_w= (const float*)d_in[17];
  const float* bno_g    = (const float*)d_in[18];
  const float* bno_b    = (const float*)d_in[19];
  const float* ff_w1    = (const float*)d_in[20];
  const float* ff_b1    = (const float*)d_in[21];
  const float* ff1_g    = (const float*)d_in[22];
  const float* ff1_b    = (const float*)d_in[23];
  const float* ff_w2    = (const float*)d_in[24];
  const float* ff_b2    = (const float*)d_in[25];
  const float* ff2_g    = (const float*)d_in[26];
  const float* ff2_b    = (const float*)d_in[27];

  float* w = (float*)d_ws;
  float* stats = w + O_STATS;
  float* st_bn1 = stats + 0;     // 32
  float* st_bn2 = stats + 32;    // 64
  float* st_img = stats + 96;    // 2
  float* aprodp = w + O_APROD;
  ushort* wbp = (ushort*)(w + O_WB);

  hipMemsetAsync(stats, 0, STATS_SZ * sizeof(float), stream);

  conv1_k<<<2048, 256, 0, stream>>>(img, conv1_w, w + O_CONV1);
  stats_chan_k<<<dim3(16, 8), 256, 0, stream>>>(w + O_CONV1, st_bn1, 16, 65536, 2);
  wprep_k<<<112, 256, 0, stream>>>(conv2_w, wbp);
  conv2_mfma_k<<<512, 256, 0, stream>>>(w + O_CONV1, st_bn1, bn1_g, bn1_b, wbp, w + O_CONV2);
  stats_chan_k<<<dim3(32, 8), 256, 0, stream>>>(w + O_CONV2, st_bn2, 32, 16384, 2);
  img_stats_k<<<128, 256, 0, stream>>>(img, st_img);
  stem_fuse_k<<<4096, 256, 0, stream>>>(w + O_CONV2, img, st_bn2, bn2_g, bn2_b,
                                        st_img, ds_w, ds_g, ds_b, w + O_TOKA);

  float* tokA = w + O_TOKA;
  float* tokB = w + O_TOKB;
  float* zx   = w + O_ZX;
  float* xbc  = w + O_XBC;
  float* dtA  = w + O_DT;
  float* dAA  = w + O_DA;
  float* y    = w + O_CONV1;   // reuse
  float* proj = w + O_CONV2;   // reuse
  float* ffh  = w + O_XBC;     // reuse (xbc dead after scan)
  float* ffo  = w + O_FFO;     // also reused as scan Hbuf
  float* Hbuf = w + O_FFO;

  for (int i = 0; i < 2; ++i) {
    float* stb = stats + 288 + i * 8192;
    gemm_mfma_k<<<dim3(18, 16), 256, 0, stream>>>(
        tokA, inproj_w + (size_t)i * EPROJ * DM_, nullptr, zx, nullptr, 2048, EPROJ, DM_);
    conv_silu_dt_k<<<9216, 256, 0, stream>>>(zx, convw + i * CONVD * 4, convb + i * CONVD,
                                             dt_bias + i * 16, A_log + i * 16, xbc, dtA, dAA);
    scan_chunk_k<0><<<1024, 256, 0, stream>>>(xbc, dtA, dAA, Dp + i * 16, Hbuf, aprodp, y);
    scan_comb_k<<<128, 256, 0, stream>>>(Hbuf, aprodp);
    scan_chunk_k<1><<<1024, 256, 0, stream>>>(xbc, dtA, dAA, Dp + i * 16, Hbuf, aprodp, y);
    rmsnorm_gate_k<<<2048, 256, 0, stream>>>(y, zx, norm_w + i * DI_);
    gemm_mfma_k<<<dim3(4, 16), 256, 0, stream>>>(
        y, outproj_w + (size_t)i * DM_ * DI_, nullptr, proj, stb, 2048, DM_, DI_);
    apply_bn_fin_k<<<4096, 256, 0, stream>>>(proj, stb, bno_g + i * DM_, bno_b + i * DM_,
                                             tokA, tokB, DM_ - 1, DM_, 1.f / 2048.f, 0);
    gemm_mfma_k<<<dim3(8, 16), 256, 0, stream>>>(
        tokB, ff_w1 + (size_t)i * FH_ * DM_, ff_b1 + i * FH_, ffh, stb + 2048, 2048, FH_, DM_);
    apply_bn_fin_k<<<8192, 256, 0, stream>>>(ffh, stb + 2048, ff1_g + i * FH_, ff1_b + i * FH_,
                                             nullptr, ffh, FH_ - 1, FH_, 1.f / 2048.f, 1);
    gemm_mfma_k<<<dim3(4, 16), 256, 0, stream>>>(
        ffh, ff_w2 + (size_t)i * DM_ * FH_, ff_b2 + i * DM_, ffo, stb + 6144, 2048, DM_, FH_);
    apply_bn_fin_k<<<4096, 256, 0, stream>>>(ffo, stb + 6144, ff2_g + i * DM_, ff2_b + i * DM_,
                                             tokB, tokA, DM_ - 1, DM_, 1.f / 2048.f, 0);
  }
  transpose_k<<<1024, 256, 0, stream>>>(tokA, (float*)d_out);
}